// Round 14
// baseline (927.182 us; speedup 1.0000x reference)
//
#include <hip/hip_runtime.h>
#include <hip/hip_bf16.h>

// SpatioTemporalGNN: B=16, N=500, T=256, F_IN=8, H=64, K=3, OUT=1
// rev 14: rev-13 post-mortem: conflicts (4.19M) were from the A-tile pitch-72
// frag reads (8-way: addr mod 128 = 16*(lr+kg+4ks)), NOT the B scatter.
//   - rev-13's b32 packing reverted everywhere (conv_mfma2 back to rev-12).
//   - k_adj_mfma: A LDS tile REMOVED. A-frags loaded global->register,
//     issued after B's global loads and before B's LDS writes + barrier
//     (fixes rev-10's latency exposure). LDS 34.8 -> 16 KB.
// Everything else identical to rev 12 (708 us baseline).

#define BB 16
#define NN 500
#define TT 256
#define FIN 8
#define HH 64

using bf16 = __hip_bfloat16;
typedef __attribute__((ext_vector_type(8))) short short8;
typedef __attribute__((ext_vector_type(4))) short short4v;
typedef __attribute__((ext_vector_type(4))) float f32x4;

static __device__ __forceinline__ short bf16bits(float v) {
    __hip_bfloat16 h = __float2bfloat16(v);
    return *reinterpret_cast<short*>(&h);
}

// ---------------- prep: adj -> padded bf16 [512][512] ----------------
__global__ __launch_bounds__(256) void k_prep_adj(
    const float* __restrict__ adj, bf16* __restrict__ adjb)
{
    int i = blockIdx.x * 256 + threadIdx.x;
    if (i < 512 * 512) {
        int r = i >> 9, c = i & 511;
        float v = (r < NN && c < NN) ? adj[r * NN + c] : 0.f;
        adjb[i] = __float2bfloat16(v);
    }
}

// ---------------- prep: pack all conv/gcn weights to bf16 MFMA-A layouts ----------------
__global__ __launch_bounds__(256) void k_prep_weights(
    const float* __restrict__ cw1, const float* __restrict__ gw1,
    const float* __restrict__ w2,  const float* __restrict__ gw2,
    bf16* __restrict__ wA1, bf16* __restrict__ gA1,
    bf16* __restrict__ wA2, bf16* __restrict__ gA2)
{
    int i = blockIdx.x * 256 + threadIdx.x;
    if (i < 2048) {
        int h = i >> 5, kp = i & 31, kk = kp >> 3, f = kp & 7;
        wA1[i] = __float2bfloat16(kk < 3 ? cw1[(h * 8 + f) * 3 + kk] : 0.f);
    } else if (i < 6144) {
        int j = i - 2048, h = j >> 6, c = j & 63;
        gA1[j] = __float2bfloat16(gw1[c * 64 + h]);
    } else if (i < 18432) {
        int j = i - 6144, kk = j / 4096, r = j & 4095, co = r >> 6, ci = r & 63;
        wA2[j] = __float2bfloat16(w2[(co * 64 + ci) * 3 + kk]);
    } else if (i < 22528) {
        int j = i - 18432, h = j >> 6, c = j & 63;
        gA2[j] = __float2bfloat16(gw2[c * 64 + h]);
    }
}

// ---------------- kernel 1: conv1 + relu + support1 via MFMA ----------------
__global__ __launch_bounds__(256) void k_conv_mfma1(
    const float* __restrict__ x, const bf16* __restrict__ wA1,
    const bf16* __restrict__ gA1, const float* __restrict__ cb,
    bf16* __restrict__ s_out)
{
    __shared__ __align__(16) short xs[256 * 64];   // 32 KB, pitch 128 B, swizzled

    const int tid = threadIdx.x;
    const int n = blockIdx.x, lb = blockIdx.y;
    const int lane = tid & 63, w = tid >> 6;
    const int lr = lane & 15, kg = lane >> 4;
    const int t0w = w * 64;

    {
        const float4* gx = (const float4*)(x + (size_t)(lb * NN + n) * (TT * FIN) + tid * 8);
        float4 a = gx[0], b = gx[1];
        short8 v;
        v[0] = bf16bits(a.x); v[1] = bf16bits(a.y); v[2] = bf16bits(a.z); v[3] = bf16bits(a.w);
        v[4] = bf16bits(b.x); v[5] = bf16bits(b.y); v[6] = bf16bits(b.z); v[7] = bf16bits(b.w);
        const int t = tid;
        *(short8*)((char*)xs + t * 128 + (16 ^ ((t & 7) << 4))) = v;
        if (t < 255)
            *(short8*)((char*)xs + (t + 1) * 128 + (0 ^ (((t + 1) & 7) << 4))) = v;
        if (t > 0)
            *(short8*)((char*)xs + (t - 1) * 128 + (32 ^ (((t - 1) & 7) << 4))) = v;
        short8 z = {0, 0, 0, 0, 0, 0, 0, 0};
        *(short8*)((char*)xs + t * 128 + (48 ^ ((t & 7) << 4))) = z;
        if (t == 0)   *(short8*)((char*)xs + 0 * 128 + (0 ^ 0)) = z;
        if (t == 255) *(short8*)((char*)xs + 255 * 128 + (32 ^ ((255 & 7) << 4))) = z;
    }
    __syncthreads();

    f32x4 acc[4][4];
    #pragma unroll
    for (int mi = 0; mi < 4; mi++)
        #pragma unroll
        for (int ti = 0; ti < 4; ti++)
            acc[mi][ti] = (f32x4){0.f, 0.f, 0.f, 0.f};

    const short* wAp = (const short*)wA1;
    {
        short8 af[4], bfr[4];
        #pragma unroll
        for (int mi = 0; mi < 4; mi++)
            af[mi] = *(const short8*)(wAp + (mi * 16 + lr) * 32 + kg * 8);
        #pragma unroll
        for (int ti = 0; ti < 4; ti++) {
            const int row = t0w + ti * 16 + lr;
            bfr[ti] = *(const short8*)((const char*)xs + row * 128 + ((kg * 16) ^ ((row & 7) << 4)));
        }
        #pragma unroll
        for (int ti = 0; ti < 4; ti++)
            #pragma unroll
            for (int mi = 0; mi < 4; mi++)
                acc[mi][ti] = __builtin_amdgcn_mfma_f32_16x16x32_bf16(af[mi], bfr[ti], acc[mi][ti], 0, 0, 0);
    }
    __syncthreads();

    {
        float cbl[16];
        #pragma unroll
        for (int mi = 0; mi < 4; mi++)
            #pragma unroll
            for (int r = 0; r < 4; r++) cbl[mi * 4 + r] = cb[mi * 16 + kg * 4 + r];
        #pragma unroll
        for (int mi = 0; mi < 4; mi++) {
            #pragma unroll
            for (int ti = 0; ti < 4; ti++) {
                const int t = t0w + ti * 16 + lr;
                short4v yv;
                #pragma unroll
                for (int r = 0; r < 4; r++)
                    yv[r] = bf16bits(fmaxf(acc[mi][ti][r] + cbl[mi * 4 + r], 0.f));
                *(short4v*)((char*)xs + t * 128 + ((mi * 32 + kg * 8) ^ ((t & 7) << 4))) = yv;
            }
        }
    }
    __syncthreads();

    f32x4 acc2[4][4];
    #pragma unroll
    for (int mi = 0; mi < 4; mi++)
        #pragma unroll
        for (int ti = 0; ti < 4; ti++)
            acc2[mi][ti] = (f32x4){0.f, 0.f, 0.f, 0.f};

    const short* gAp = (const short*)gA1;
    #pragma unroll
    for (int ks = 0; ks < 2; ks++) {
        short8 af[4], bfr[4];
        #pragma unroll
        for (int mi = 0; mi < 4; mi++)
            af[mi] = *(const short8*)(gAp + (mi * 16 + lr) * 64 + ks * 32 + kg * 8);
        #pragma unroll
        for (int ti = 0; ti < 4; ti++) {
            const int t = t0w + ti * 16 + lr;
            bfr[ti] = *(const short8*)((const char*)xs + t * 128 + ((ks * 64 + kg * 16) ^ ((t & 7) << 4)));
        }
        #pragma unroll
        for (int ti = 0; ti < 4; ti++)
            #pragma unroll
            for (int mi = 0; mi < 4; mi++)
                acc2[mi][ti] = __builtin_amdgcn_mfma_f32_16x16x32_bf16(af[mi], bfr[ti], acc2[mi][ti], 0, 0, 0);
    }

    #pragma unroll
    for (int mi = 0; mi < 4; mi++) {
        #pragma unroll
        for (int r = 0; r < 4; r++) {
            const int h = mi * 16 + kg * 4 + r;
            bf16* orow = s_out + ((size_t)(lb * 64 + h) * NN + n) * TT + t0w + lr;
            #pragma unroll
            for (int ti = 0; ti < 4; ti++)
                orow[ti * 16] = __float2bfloat16(acc2[mi][ti][r]);
        }
    }
}

// ---------------- kernel 2/4: adj GEMM via MFMA + bias + relu + BN ----------------
// A-frags: global->register, issued early each round (adjb is L2-hot 512KB).
// B^T staged [t 128][k 64] swizzled via scalar-u16 scatter (rev-12, ~2-way).
// XCD-aware 1-D grid decode. LDS = 16 KB (BtS only).
#define SWZ_T(t) (((((t) & 7) ^ (((t) >> 5) << 1)) & 7) << 4)

template<bool MEAN>
__global__ __launch_bounds__(256) void k_adj_mfma(
    const bf16* __restrict__ s_in, const bf16* __restrict__ adjb,
    const float* __restrict__ gb, const float* __restrict__ bn_g,
    const float* __restrict__ bn_b, const float* __restrict__ bn_m,
    const float* __restrict__ bn_v, bf16* __restrict__ h_out,
    float* __restrict__ pf, int nbh)
{
    __shared__ __align__(16) short BtS[128 * 64];   // B^T [t 128][k 64], swizzled (16 KB)

    const int tid = threadIdx.x;
    const int id = blockIdx.x;
    const int xcd = id & 7;
    const int jj = id >> 3;
    const int mt = jj & 3;
    const int g = ((jj >> 2) << 3) + xcd;
    const int bh = g >> 1;
    const int m0 = mt * 128;
    const int t0 = (g & 1) * 128;
    const int h = bh & 63;

    const int lane = tid & 63;
    const int lr = lane & 15;
    const int kg = lane >> 4;
    const int w = tid >> 6;
    const int wr = w >> 1, wc = w & 1;

    f32x4 acc[4][4];
    #pragma unroll
    for (int mi = 0; mi < 4; mi++)
        #pragma unroll
        for (int ti = 0; ti < 4; ti++)
            acc[mi][ti] = (f32x4){0.f, 0.f, 0.f, 0.f};

    // staging maps (constant per thread) — rev-9/12 B map
    const int sk = tid >> 2, tseg = (tid & 3) * 32;      // B: k, 32-t segment
    const bf16* sslice = s_in + (size_t)bh * (NN * TT) + t0;
    const short* adjp = (const short*)adjb;
    // per-thread A row base (frag row = m0 + wr*64 + mi*16 + lr)
    const short* arow = adjp + (size_t)(m0 + wr * 64 + lr) * 512 + kg * 8;

    for (int rnd = 0; rnd < 8; rnd++) {
        const int k0 = rnd * 64;
        // ---- B global loads (issued first: B LDS-writes need only these) ----
        const int kglob = k0 + sk;
        short8 v0, v1, v2, v3;
        if (kglob < NN) {
            const short8* gg = (const short8*)(sslice + (size_t)kglob * TT + tseg);
            v0 = gg[0]; v1 = gg[1]; v2 = gg[2]; v3 = gg[3];
        } else {
            v0 = (short8){0,0,0,0,0,0,0,0}; v1 = v0; v2 = v0; v3 = v0;
        }
        // ---- A-frag loads global->reg (issued early; hide under staging+barrier) ----
        short8 af[4][2];
        #pragma unroll
        for (int mi = 0; mi < 4; mi++)
            #pragma unroll
            for (int ks = 0; ks < 2; ks++)
                af[mi][ks] = *(const short8*)(arow + (size_t)(mi * 16) * 512 + k0 + ks * 32);
        // ---- B LDS scatter (rev-12: scalar u16, ~2-way) ----
        {
            const int kslot = (sk >> 3) << 4;
            const int kfine = (sk & 7) * 2;
            #pragma unroll
            for (int u = 0; u < 4; u++) {
                short8 v = (u == 0) ? v0 : (u == 1) ? v1 : (u == 2) ? v2 : v3;
                #pragma unroll
                for (int j = 0; j < 8; j++) {
                    const int t = tseg + u * 8 + j;
                    *(short*)((char*)BtS + t * 128 + (kslot ^ SWZ_T(t)) + kfine) = v[j];
                }
            }
        }
        __syncthreads();

        #pragma unroll
        for (int ks = 0; ks < 2; ks++) {
            short8 bfr[4];
            #pragma unroll
            for (int ti = 0; ti < 4; ti++) {
                const int t = wc * 64 + ti * 16 + lr;
                bfr[ti] = *(const short8*)((const char*)BtS + t * 128 + ((((ks * 4 + kg) << 4)) ^ SWZ_T(t)));
            }
            #pragma unroll
            for (int ti = 0; ti < 4; ti++)
                #pragma unroll
                for (int mi = 0; mi < 4; mi++)
                    acc[mi][ti] = __builtin_amdgcn_mfma_f32_16x16x32_bf16(af[mi][ks], bfr[ti], acc[mi][ti], 0, 0, 0);
        }
        __syncthreads();
    }

    const float bias  = gb[h];
    const float scale = bn_g[h] / sqrtf(bn_v[h] + 1e-5f);
    const float shift = bn_b[h] - bn_m[h] * scale;

    if constexpr (!MEAN) {
        #pragma unroll
        for (int mi = 0; mi < 4; mi++) {
            const int mbase = m0 + wr * 64 + mi * 16 + kg * 4;
            #pragma unroll
            for (int r = 0; r < 4; r++) {
                const int m = mbase + r;
                if (m < NN) {
                    bf16* orow = h_out + ((size_t)bh * NN + m) * TT + t0 + wc * 64 + lr;
                    #pragma unroll
                    for (int ti = 0; ti < 4; ti++) {
                        float v = fmaxf(acc[mi][ti][r] + bias, 0.f);
                        orow[ti * 16] = __float2bfloat16(v * scale + shift);
                    }
                }
            }
        }
    } else {
        float sums[4][4];
        #pragma unroll
        for (int mi = 0; mi < 4; mi++)
            #pragma unroll
            for (int r = 0; r < 4; r++) {
                float s = 0.f;
                #pragma unroll
                for (int ti = 0; ti < 4; ti++)
                    s += fmaxf(acc[mi][ti][r] + bias, 0.f) * scale + shift;
                sums[mi][r] = s;
            }
        #pragma unroll
        for (int off = 1; off < 16; off <<= 1)
            #pragma unroll
            for (int mi = 0; mi < 4; mi++)
                #pragma unroll
                for (int r = 0; r < 4; r++)
                    sums[mi][r] += __shfl_xor(sums[mi][r], off, 64);
        if (lr == 0) {
            const size_t stride = (size_t)nbh * NN;
            float* pfb = pf + ((size_t)((g & 1) * 2 + wc)) * stride + (size_t)bh * NN;
            #pragma unroll
            for (int mi = 0; mi < 4; mi++) {
                const int m = m0 + wr * 64 + mi * 16 + kg * 4;
                if (m < NN) {
                    float4 v = make_float4(sums[mi][0], sums[mi][1], sums[mi][2], sums[mi][3]);
                    *(float4*)(pfb + m) = v;
                }
            }
        }
    }
}

// ---------------- kernel 3: conv2 + relu + support2 via MFMA (rev-12) ----------------
__global__ __launch_bounds__(256) void k_conv_mfma2(
    const bf16* __restrict__ hin, const bf16* __restrict__ wA,
    const bf16* __restrict__ gA, const float* __restrict__ cb,
    bf16* __restrict__ s_out)
{
    __shared__ __align__(16) short xs[258 * 64];   // 33 KB, swizzled

    const int tid = threadIdx.x;
    const int n = blockIdx.x, lb = blockIdx.y;
    const int lane = tid & 63, w = tid >> 6;
    const int lr = lane & 15, kg = lane >> 4;
    const int t0w = w * 64;

    const bf16* base = hin + ((size_t)lb * 64 * NN + n) * TT;

    {
        const int cin = tid >> 2, tq = (tid & 3) * 64;
        const short* gsrc = (const short*)(base + (size_t)cin * (NN * TT) + tq);
        #pragma unroll
        for (int i = 0; i < 8; i++) {
            short8 v = *(const short8*)(gsrc + i * 8);
            #pragma unroll
            for (int j = 0; j < 8; j++) {
                const int row = tq + i * 8 + j + 1;
                const int addr = row * 128 + ((cin * 2) ^ ((row & 7) << 4));
                *(short*)((char*)xs + addr) = v[j];
            }
        }
        if (tid < 64) {
            *(short*)((char*)xs + (tid * 2)) = 0;
            *(short*)((char*)xs + 257 * 128 + ((tid * 2) ^ 16)) = 0;
        }
    }
    __syncthreads();

    f32x4 acc[4][4];
    #pragma unroll
    for (int mi = 0; mi < 4; mi++)
        #pragma unroll
        for (int ti = 0; ti < 4; ti++)
            acc[mi][ti] = (f32x4){0.f, 0.f, 0.f, 0.f};

    const short* wAp = (const short*)wA;
    #pragma unroll
    for (int kk = 0; kk < 3; kk++) {
        #pragma unroll
        for (int ks = 0; ks < 2; ks++) {
            short8 af[4], bfr[4];
            #pragma unroll
            for (int mi = 0; mi < 4; mi++)
                af[mi] = *(const short8*)(wAp + ((kk * 64 + mi * 16 + lr) * 64 + ks * 32 + kg * 8));
            #pragma unroll
            for (int ti = 0; ti < 4; ti++) {
                const int row = t0w + ti * 16 + lr + kk;
                const int addr = row * 128 + ((ks * 64 + kg * 16) ^ ((row & 7) << 4));
                bfr[ti] = *(const short8*)((const char*)xs + addr);
            }
            #pragma unroll
            for (int ti = 0; ti < 4; ti++)
                #pragma unroll
                for (int mi = 0; mi < 4; mi++)
                    acc[mi][ti] = __builtin_amdgcn_mfma_f32_16x16x32_bf16(af[mi], bfr[ti], acc[mi][ti], 0, 0, 0);
        }
    }
    __syncthreads();

    {
        float cbl[16];
        #pragma unroll
        for (int mi = 0; mi < 4; mi++)
            #pragma unroll
            for (int r = 0; r < 4; r++) cbl[mi * 4 + r] = cb[mi * 16 + kg * 4 + r];
        #pragma unroll
        for (int mi = 0; mi < 4; mi++) {
            #pragma unroll
            for (int ti = 0; ti < 4; ti++) {
                const int t = t0w + ti * 16 + lr;
                short4v yv;
                #pragma unroll
                for (int r = 0; r < 4; r++)
                    yv[r] = bf16bits(fmaxf(acc[mi][ti][r] + cbl[mi * 4 + r], 0.f));
                const int addr = t * 128 + ((mi * 32 + kg * 8) ^ ((t & 7) << 4));
                *(short4v*)((char*)xs + addr) = yv;
            }
        }
    }
    __syncthreads();

    f32x4 acc2[4][4];
    #pragma unroll
    for (int mi = 0; mi < 4; mi++)
        #pragma unroll
        for (int ti = 0; ti < 4; ti++)
            acc2[mi][ti] = (f32x4){0.f, 0.f, 0.f, 0.f};

    const short* gAp = (const short*)gA;
    #pragma unroll
    for (int ks = 0; ks < 2; ks++) {
        short8 af[4], bfr[4];
        #pragma unroll
        for (int mi = 0; mi < 4; mi++)
            af[mi] = *(const short8*)(gAp + ((mi * 16 + lr) * 64 + ks * 32 + kg * 8));
        #pragma unroll
        for (int ti = 0; ti < 4; ti++) {
            const int t = t0w + ti * 16 + lr;
            const int addr = t * 128 + ((ks * 64 + kg * 16) ^ ((t & 7) << 4));
            bfr[ti] = *(const short8*)((const char*)xs + addr);
        }
        #pragma unroll
        for (int ti = 0; ti < 4; ti++)
            #pragma unroll
            for (int mi = 0; mi < 4; mi++)
                acc2[mi][ti] = __builtin_amdgcn_mfma_f32_16x16x32_bf16(af[mi], bfr[ti], acc2[mi][ti], 0, 0, 0);
    }

    #pragma unroll
    for (int mi = 0; mi < 4; mi++) {
        #pragma unroll
        for (int r = 0; r < 4; r++) {
            const int h = mi * 16 + kg * 4 + r;
            bf16* orow = s_out + ((size_t)(lb * 64 + h) * NN + n) * TT + t0w + lr;
            #pragma unroll
            for (int ti = 0; ti < 4; ti++)
                orow[ti * 16] = __float2bfloat16(acc2[mi][ti][r]);
        }
    }
}

// ---------------- kernel 5: mean (from partials) + MLP ----------------
__global__ __launch_bounds__(64) void k_mlp(
    const float* __restrict__ pf, int nbh,
    const float* __restrict__ w1, const float* __restrict__ b1,
    const float* __restrict__ w2, const float* __restrict__ b2,
    float* __restrict__ out)
{
    __shared__ float mm[64];
    __shared__ float hid[32];
    const int n = blockIdx.x, lb = blockIdx.y, tid = threadIdx.x;

    const size_t stride = (size_t)nbh * NN;
    const size_t idx = (size_t)(lb * 64 + tid) * NN + n;
    float s = pf[idx] + pf[stride + idx] + pf[2 * stride + idx] + pf[3 * stride + idx];
    mm[tid] = s * (1.f / 256.f);
    __syncthreads();
    if (tid < 32) {
        float a = b1[tid];
        #pragma unroll
        for (int c = 0; c < 64; c++) a += mm[c] * w1[c * 32 + tid];
        hid[tid] = fmaxf(a, 0.f);
    }
    __syncthreads();
    if (tid == 0) {
        float a = b2[0];
        #pragma unroll
        for (int j = 0; j < 32; j++) a += hid[j] * w2[j];
        out[lb * NN + n] = a;
    }
}

extern "C" void kernel_launch(void* const* d_in, const int* in_sizes, int n_in,
                              void* d_out, int out_size, void* d_ws, size_t ws_size,
                              hipStream_t stream) {
    const float* x       = (const float*)d_in[0];
    const float* adj     = (const float*)d_in[1];
    const float* conv_w1 = (const float*)d_in[2];
    const float* conv_b1 = (const float*)d_in[3];
    const float* conv_w2 = (const float*)d_in[4];
    const float* conv_b2 = (const float*)d_in[5];
    const float* gcn_w1  = (const float*)d_in[6];
    const float* gcn_b1  = (const float*)d_in[7];
    const float* gcn_w2  = (const float*)d_in[8];
    const float* gcn_b2  = (const float*)d_in[9];
    const float* bn_g1   = (const float*)d_in[10];
    const float* bn_be1  = (const float*)d_in[11];
    const float* bn_m1   = (const float*)d_in[12];
    const float* bn_v1   = (const float*)d_in[13];
    const float* bn_g2   = (const float*)d_in[14];
    const float* bn_be2  = (const float*)d_in[15];
    const float* bn_m2   = (const float*)d_in[16];
    const float* bn_v2   = (const float*)d_in[17];
    const float* out_w1  = (const float*)d_in[18];
    const float* out_b1  = (const float*)d_in[19];
    const float* out_w2  = (const float*)d_in[20];
    const float* out_b2  = (const float*)d_in[21];
    float* out = (float*)d_out;

    const size_t per_b = (size_t)HH * NN * TT;             // 8,192,000 elems/batch
    const size_t reserve = 1 << 20;
    const size_t bytes_per_b_both = per_b * 2 * 2;
    int chunk = (int)((ws_size > reserve ? ws_size - reserve : 0) / bytes_per_b_both);
    if (chunk > BB) chunk = BB;
    if (chunk < 1) chunk = 1;

    char* ws = (char*)d_ws;
    bf16* adjb = (bf16*)ws;                                // 524,288 B
    bf16* wA2  = (bf16*)(ws + 0x80000);                    // 24,576 B
    bf16* gA2  = (bf16*)(ws + 0x80000 + 24576);            // 8,192 B
    bf16* wA1  = (bf16*)(ws + 0x80000 + 32768);            // 4,096 B
    bf16* gA1  = (bf16*)(ws + 0x80000 + 36864);            // 8,192 B
    bf16* bufA = (bf16*)(ws + reserve);
    bf16* bufB = bufA + (size_t)chunk * per_b;

    k_prep_adj<<<1024, 256, 0, stream>>>(adj, adjb);
    k_prep_weights<<<88, 256, 0, stream>>>(conv_w1, gcn_w1, conv_w2, gcn_w2,
                                           wA1, gA1, wA2, gA2);

    for (int b0 = 0; b0 < BB; b0 += chunk) {
        const int nb = (BB - b0) < chunk ? (BB - b0) : chunk;
        const int nbh = nb * 64;
        float* pf = (float*)bufB;   // bufB is dead during layer-2 adj + mlp

        k_conv_mfma1<<<dim3(NN, nb), 256, 0, stream>>>(
            x + (size_t)b0 * NN * TT * FIN, wA1, gA1, conv_b1, bufA);

        k_adj_mfma<false><<<dim3(8 * nbh), 256, 0, stream>>>(
            bufA, adjb, gcn_b1, bn_g1, bn_be1, bn_m1, bn_v1, bufB, nullptr, nbh);

        k_conv_mfma2<<<dim3(NN, nb), 256, 0, stream>>>(
            bufB, wA2, gA2, conv_b2, bufA);

        k_adj_mfma<true><<<dim3(8 * nbh), 256, 0, stream>>>(
            bufA, adjb, gcn_b2, bn_g2, bn_be2, bn_m2, bn_v2, nullptr, pf, nbh);

        k_mlp<<<dim3(NN, nb), 64, 0, stream>>>(
            pf, nbh, out_w1, out_b1, out_w2, out_b2, out + (size_t)b0 * NN);
    }
}

// Round 15
// 746.386 us; speedup vs baseline: 1.2422x; 1.2422x over previous
//
#include <hip/hip_runtime.h>
#include <hip/hip_bf16.h>

// SpatioTemporalGNN: B=16, N=500, T=256, F_IN=8, H=64, K=3, OUT=1
// rev 15 = rev 12 (708us anchor) + ONE change: k_adj_mfma B-loads software-
// pipelined one round ahead (prologue + rotate; loads issued right after
// barrier1 so latency hides under round r's 32 MFMAs). Layouts, swizzle,
// A-staging, grid decode, epilogues: byte-identical to rev 12.
// rev-13/14 lessons: per-thread global loads must stay >=64B contiguous;
// A stays LDS-staged; conflict counter is quantized (2^22 steps) and small.

#define BB 16
#define NN 500
#define TT 256
#define FIN 8
#define HH 64

using bf16 = __hip_bfloat16;
typedef __attribute__((ext_vector_type(8))) short short8;
typedef __attribute__((ext_vector_type(4))) short short4v;
typedef __attribute__((ext_vector_type(4))) float f32x4;

static __device__ __forceinline__ short bf16bits(float v) {
    __hip_bfloat16 h = __float2bfloat16(v);
    return *reinterpret_cast<short*>(&h);
}

// ---------------- prep: adj -> padded bf16 [512][512] ----------------
__global__ __launch_bounds__(256) void k_prep_adj(
    const float* __restrict__ adj, bf16* __restrict__ adjb)
{
    int i = blockIdx.x * 256 + threadIdx.x;
    if (i < 512 * 512) {
        int r = i >> 9, c = i & 511;
        float v = (r < NN && c < NN) ? adj[r * NN + c] : 0.f;
        adjb[i] = __float2bfloat16(v);
    }
}

// ---------------- prep: pack all conv/gcn weights to bf16 MFMA-A layouts ----------------
__global__ __launch_bounds__(256) void k_prep_weights(
    const float* __restrict__ cw1, const float* __restrict__ gw1,
    const float* __restrict__ w2,  const float* __restrict__ gw2,
    bf16* __restrict__ wA1, bf16* __restrict__ gA1,
    bf16* __restrict__ wA2, bf16* __restrict__ gA2)
{
    int i = blockIdx.x * 256 + threadIdx.x;
    if (i < 2048) {
        int h = i >> 5, kp = i & 31, kk = kp >> 3, f = kp & 7;
        wA1[i] = __float2bfloat16(kk < 3 ? cw1[(h * 8 + f) * 3 + kk] : 0.f);
    } else if (i < 6144) {
        int j = i - 2048, h = j >> 6, c = j & 63;
        gA1[j] = __float2bfloat16(gw1[c * 64 + h]);
    } else if (i < 18432) {
        int j = i - 6144, kk = j / 4096, r = j & 4095, co = r >> 6, ci = r & 63;
        wA2[j] = __float2bfloat16(w2[(co * 64 + ci) * 3 + kk]);
    } else if (i < 22528) {
        int j = i - 18432, h = j >> 6, c = j & 63;
        gA2[j] = __float2bfloat16(gw2[c * 64 + h]);
    }
}

// ---------------- kernel 1: conv1 + relu + support1 via MFMA ----------------
__global__ __launch_bounds__(256) void k_conv_mfma1(
    const float* __restrict__ x, const bf16* __restrict__ wA1,
    const bf16* __restrict__ gA1, const float* __restrict__ cb,
    bf16* __restrict__ s_out)
{
    __shared__ __align__(16) short xs[256 * 64];   // 32 KB, pitch 128 B, swizzled

    const int tid = threadIdx.x;
    const int n = blockIdx.x, lb = blockIdx.y;
    const int lane = tid & 63, w = tid >> 6;
    const int lr = lane & 15, kg = lane >> 4;
    const int t0w = w * 64;

    {
        const float4* gx = (const float4*)(x + (size_t)(lb * NN + n) * (TT * FIN) + tid * 8);
        float4 a = gx[0], b = gx[1];
        short8 v;
        v[0] = bf16bits(a.x); v[1] = bf16bits(a.y); v[2] = bf16bits(a.z); v[3] = bf16bits(a.w);
        v[4] = bf16bits(b.x); v[5] = bf16bits(b.y); v[6] = bf16bits(b.z); v[7] = bf16bits(b.w);
        const int t = tid;
        *(short8*)((char*)xs + t * 128 + (16 ^ ((t & 7) << 4))) = v;
        if (t < 255)
            *(short8*)((char*)xs + (t + 1) * 128 + (0 ^ (((t + 1) & 7) << 4))) = v;
        if (t > 0)
            *(short8*)((char*)xs + (t - 1) * 128 + (32 ^ (((t - 1) & 7) << 4))) = v;
        short8 z = {0, 0, 0, 0, 0, 0, 0, 0};
        *(short8*)((char*)xs + t * 128 + (48 ^ ((t & 7) << 4))) = z;
        if (t == 0)   *(short8*)((char*)xs + 0 * 128 + (0 ^ 0)) = z;
        if (t == 255) *(short8*)((char*)xs + 255 * 128 + (32 ^ ((255 & 7) << 4))) = z;
    }
    __syncthreads();

    f32x4 acc[4][4];
    #pragma unroll
    for (int mi = 0; mi < 4; mi++)
        #pragma unroll
        for (int ti = 0; ti < 4; ti++)
            acc[mi][ti] = (f32x4){0.f, 0.f, 0.f, 0.f};

    const short* wAp = (const short*)wA1;
    {
        short8 af[4], bfr[4];
        #pragma unroll
        for (int mi = 0; mi < 4; mi++)
            af[mi] = *(const short8*)(wAp + (mi * 16 + lr) * 32 + kg * 8);
        #pragma unroll
        for (int ti = 0; ti < 4; ti++) {
            const int row = t0w + ti * 16 + lr;
            bfr[ti] = *(const short8*)((const char*)xs + row * 128 + ((kg * 16) ^ ((row & 7) << 4)));
        }
        #pragma unroll
        for (int ti = 0; ti < 4; ti++)
            #pragma unroll
            for (int mi = 0; mi < 4; mi++)
                acc[mi][ti] = __builtin_amdgcn_mfma_f32_16x16x32_bf16(af[mi], bfr[ti], acc[mi][ti], 0, 0, 0);
    }
    __syncthreads();

    {
        float cbl[16];
        #pragma unroll
        for (int mi = 0; mi < 4; mi++)
            #pragma unroll
            for (int r = 0; r < 4; r++) cbl[mi * 4 + r] = cb[mi * 16 + kg * 4 + r];
        #pragma unroll
        for (int mi = 0; mi < 4; mi++) {
            #pragma unroll
            for (int ti = 0; ti < 4; ti++) {
                const int t = t0w + ti * 16 + lr;
                short4v yv;
                #pragma unroll
                for (int r = 0; r < 4; r++)
                    yv[r] = bf16bits(fmaxf(acc[mi][ti][r] + cbl[mi * 4 + r], 0.f));
                *(short4v*)((char*)xs + t * 128 + ((mi * 32 + kg * 8) ^ ((t & 7) << 4))) = yv;
            }
        }
    }
    __syncthreads();

    f32x4 acc2[4][4];
    #pragma unroll
    for (int mi = 0; mi < 4; mi++)
        #pragma unroll
        for (int ti = 0; ti < 4; ti++)
            acc2[mi][ti] = (f32x4){0.f, 0.f, 0.f, 0.f};

    const short* gAp = (const short*)gA1;
    #pragma unroll
    for (int ks = 0; ks < 2; ks++) {
        short8 af[4], bfr[4];
        #pragma unroll
        for (int mi = 0; mi < 4; mi++)
            af[mi] = *(const short8*)(gAp + (mi * 16 + lr) * 64 + ks * 32 + kg * 8);
        #pragma unroll
        for (int ti = 0; ti < 4; ti++) {
            const int t = t0w + ti * 16 + lr;
            bfr[ti] = *(const short8*)((const char*)xs + t * 128 + ((ks * 64 + kg * 16) ^ ((t & 7) << 4)));
        }
        #pragma unroll
        for (int ti = 0; ti < 4; ti++)
            #pragma unroll
            for (int mi = 0; mi < 4; mi++)
                acc2[mi][ti] = __builtin_amdgcn_mfma_f32_16x16x32_bf16(af[mi], bfr[ti], acc2[mi][ti], 0, 0, 0);
    }

    #pragma unroll
    for (int mi = 0; mi < 4; mi++) {
        #pragma unroll
        for (int r = 0; r < 4; r++) {
            const int h = mi * 16 + kg * 4 + r;
            bf16* orow = s_out + ((size_t)(lb * 64 + h) * NN + n) * TT + t0w + lr;
            #pragma unroll
            for (int ti = 0; ti < 4; ti++)
                orow[ti * 16] = __float2bfloat16(acc2[mi][ti][r]);
        }
    }
}

// ---------------- kernel 2/4: adj GEMM via MFMA + bias + relu + BN ----------------
// rev-12 body + B-load software pipeline (prologue + rotate). A staged
// [m 128][k 64] pitch 72 (b128); B^T staged [t 128][k 64] swizzled via
// scalar-u16 scatter. XCD-aware 1-D grid decode.
#define SWZ_T(t) (((((t) & 7) ^ (((t) >> 5) << 1)) & 7) << 4)

template<bool MEAN>
__global__ __launch_bounds__(256) void k_adj_mfma(
    const bf16* __restrict__ s_in, const bf16* __restrict__ adjb,
    const float* __restrict__ gb, const float* __restrict__ bn_g,
    const float* __restrict__ bn_b, const float* __restrict__ bn_m,
    const float* __restrict__ bn_v, bf16* __restrict__ h_out,
    float* __restrict__ pf, int nbh)
{
    __shared__ __align__(16) short AsS[128 * 72];   // A [m 128][k 64], pitch 72 (18.4 KB)
    __shared__ __align__(16) short BtS[128 * 64];   // B^T [t 128][k 64], swizzled (16 KB)

    const int tid = threadIdx.x;
    const int id = blockIdx.x;
    const int xcd = id & 7;
    const int jj = id >> 3;
    const int mt = jj & 3;
    const int g = ((jj >> 2) << 3) + xcd;
    const int bh = g >> 1;
    const int m0 = mt * 128;
    const int t0 = (g & 1) * 128;
    const int h = bh & 63;

    const int lane = tid & 63;
    const int lr = lane & 15;
    const int kg = lane >> 4;
    const int w = tid >> 6;
    const int wr = w >> 1, wc = w & 1;

    f32x4 acc[4][4];
    #pragma unroll
    for (int mi = 0; mi < 4; mi++)
        #pragma unroll
        for (int ti = 0; ti < 4; ti++)
            acc[mi][ti] = (f32x4){0.f, 0.f, 0.f, 0.f};

    // staging maps (constant per thread) — rev-9/12 B map
    const int sk = tid >> 2, tseg = (tid & 3) * 32;      // B: k, 32-t segment
    const bf16* sslice = s_in + (size_t)bh * (NN * TT) + t0;

    // ---- prologue: load B for round 0 ----
    short8 pv0, pv1, pv2, pv3;
    {
        const int kglob = sk;
        if (kglob < NN) {
            const short8* gg = (const short8*)(sslice + (size_t)kglob * TT + tseg);
            pv0 = gg[0]; pv1 = gg[1]; pv2 = gg[2]; pv3 = gg[3];
        } else {
            pv0 = (short8){0,0,0,0,0,0,0,0}; pv1 = pv0; pv2 = pv0; pv3 = pv0;
        }
    }

    for (int rnd = 0; rnd < 8; rnd++) {
        const int k0 = rnd * 64;
        // ---- stage A: adjb[m0+ar][k0+ah .. +31] ----
        {
            const int ar = tid >> 1, ah = (tid & 1) * 32;
            const float4* src = (const float4*)(adjb + (size_t)(m0 + ar) * 512 + k0 + ah);
            float4* dst = (float4*)(AsS + ar * 72 + ah);
            dst[0] = src[0]; dst[1] = src[1]; dst[2] = src[2]; dst[3] = src[3];
        }
        // ---- B LDS scatter from prefetched regs (rev-12: scalar u16, ~2-way) ----
        {
            const int kslot = (sk >> 3) << 4;
            const int kfine = (sk & 7) * 2;
            #pragma unroll
            for (int u = 0; u < 4; u++) {
                short8 v = (u == 0) ? pv0 : (u == 1) ? pv1 : (u == 2) ? pv2 : pv3;
                #pragma unroll
                for (int j = 0; j < 8; j++) {
                    const int t = tseg + u * 8 + j;
                    *(short*)((char*)BtS + t * 128 + (kslot ^ SWZ_T(t)) + kfine) = v[j];
                }
            }
        }
        __syncthreads();

        // ---- prefetch B for round rnd+1 (latency hides under the MFMAs) ----
        short8 nv0, nv1, nv2, nv3;
        {
            const int kglob = k0 + 64 + sk;
            if (kglob < NN) {
                const short8* gg = (const short8*)(sslice + (size_t)kglob * TT + tseg);
                nv0 = gg[0]; nv1 = gg[1]; nv2 = gg[2]; nv3 = gg[3];
            } else {
                nv0 = (short8){0,0,0,0,0,0,0,0}; nv1 = nv0; nv2 = nv0; nv3 = nv0;
            }
        }

        #pragma unroll
        for (int ks = 0; ks < 2; ks++) {
            short8 af[4], bfr[4];
            #pragma unroll
            for (int mi = 0; mi < 4; mi++)
                af[mi] = *(const short8*)(AsS + (wr * 64 + mi * 16 + lr) * 72 + ks * 32 + kg * 8);
            #pragma unroll
            for (int ti = 0; ti < 4; ti++) {
                const int t = wc * 64 + ti * 16 + lr;
                bfr[ti] = *(const short8*)((const char*)BtS + t * 128 + ((((ks * 4 + kg) << 4)) ^ SWZ_T(t)));
            }
            #pragma unroll
            for (int ti = 0; ti < 4; ti++)
                #pragma unroll
                for (int mi = 0; mi < 4; mi++)
                    acc[mi][ti] = __builtin_amdgcn_mfma_f32_16x16x32_bf16(af[mi], bfr[ti], acc[mi][ti], 0, 0, 0);
        }
        __syncthreads();

        pv0 = nv0; pv1 = nv1; pv2 = nv2; pv3 = nv3;
    }

    const float bias  = gb[h];
    const float scale = bn_g[h] / sqrtf(bn_v[h] + 1e-5f);
    const float shift = bn_b[h] - bn_m[h] * scale;

    if constexpr (!MEAN) {
        #pragma unroll
        for (int mi = 0; mi < 4; mi++) {
            const int mbase = m0 + wr * 64 + mi * 16 + kg * 4;
            #pragma unroll
            for (int r = 0; r < 4; r++) {
                const int m = mbase + r;
                if (m < NN) {
                    bf16* orow = h_out + ((size_t)bh * NN + m) * TT + t0 + wc * 64 + lr;
                    #pragma unroll
                    for (int ti = 0; ti < 4; ti++) {
                        float v = fmaxf(acc[mi][ti][r] + bias, 0.f);
                        orow[ti * 16] = __float2bfloat16(v * scale + shift);
                    }
                }
            }
        }
    } else {
        float sums[4][4];
        #pragma unroll
        for (int mi = 0; mi < 4; mi++)
            #pragma unroll
            for (int r = 0; r < 4; r++) {
                float s = 0.f;
                #pragma unroll
                for (int ti = 0; ti < 4; ti++)
                    s += fmaxf(acc[mi][ti][r] + bias, 0.f) * scale + shift;
                sums[mi][r] = s;
            }
        #pragma unroll
        for (int off = 1; off < 16; off <<= 1)
            #pragma unroll
            for (int mi = 0; mi < 4; mi++)
                #pragma unroll
                for (int r = 0; r < 4; r++)
                    sums[mi][r] += __shfl_xor(sums[mi][r], off, 64);
        if (lr == 0) {
            const size_t stride = (size_t)nbh * NN;
            float* pfb = pf + ((size_t)((g & 1) * 2 + wc)) * stride + (size_t)bh * NN;
            #pragma unroll
            for (int mi = 0; mi < 4; mi++) {
                const int m = m0 + wr * 64 + mi * 16 + kg * 4;
                if (m < NN) {
                    float4 v = make_float4(sums[mi][0], sums[mi][1], sums[mi][2], sums[mi][3]);
                    *(float4*)(pfb + m) = v;
                }
            }
        }
    }
}

// ---------------- kernel 3: conv2 + relu + support2 via MFMA (rev-12) ----------------
__global__ __launch_bounds__(256) void k_conv_mfma2(
    const bf16* __restrict__ hin, const bf16* __restrict__ wA,
    const bf16* __restrict__ gA, const float* __restrict__ cb,
    bf16* __restrict__ s_out)
{
    __shared__ __align__(16) short xs[258 * 64];   // 33 KB, swizzled

    const int tid = threadIdx.x;
    const int n = blockIdx.x, lb = blockIdx.y;
    const int lane = tid & 63, w = tid >> 6;
    const int lr = lane & 15, kg = lane >> 4;
    const int t0w = w * 64;

    const bf16* base = hin + ((size_t)lb * 64 * NN + n) * TT;

    {
        const int cin = tid >> 2, tq = (tid & 3) * 64;
        const short* gsrc = (const short*)(base + (size_t)cin * (NN * TT) + tq);
        #pragma unroll
        for (int i = 0; i < 8; i++) {
            short8 v = *(const short8*)(gsrc + i * 8);
            #pragma unroll
            for (int j = 0; j < 8; j++) {
                const int row = tq + i * 8 + j + 1;
                const int addr = row * 128 + ((cin * 2) ^ ((row & 7) << 4));
                *(short*)((char*)xs + addr) = v[j];
            }
        }
        if (tid < 64) {
            *(short*)((char*)xs + (tid * 2)) = 0;
            *(short*)((char*)xs + 257 * 128 + ((tid * 2) ^ 16)) = 0;
        }
    }
    __syncthreads();

    f32x4 acc[4][4];
    #pragma unroll
    for (int mi = 0; mi < 4; mi++)
        #pragma unroll
        for (int ti = 0; ti < 4; ti++)
            acc[mi][ti] = (f32x4){0.f, 0.f, 0.f, 0.f};

    const short* wAp = (const short*)wA;
    #pragma unroll
    for (int kk = 0; kk < 3; kk++) {
        #pragma unroll
        for (int ks = 0; ks < 2; ks++) {
            short8 af[4], bfr[4];
            #pragma unroll
            for (int mi = 0; mi < 4; mi++)
                af[mi] = *(const short8*)(wAp + ((kk * 64 + mi * 16 + lr) * 64 + ks * 32 + kg * 8));
            #pragma unroll
            for (int ti = 0; ti < 4; ti++) {
                const int row = t0w + ti * 16 + lr + kk;
                const int addr = row * 128 + ((ks * 64 + kg * 16) ^ ((row & 7) << 4));
                bfr[ti] = *(const short8*)((const char*)xs + addr);
            }
            #pragma unroll
            for (int ti = 0; ti < 4; ti++)
                #pragma unroll
                for (int mi = 0; mi < 4; mi++)
                    acc[mi][ti] = __builtin_amdgcn_mfma_f32_16x16x32_bf16(af[mi], bfr[ti], acc[mi][ti], 0, 0, 0);
        }
    }
    __syncthreads();

    {
        float cbl[16];
        #pragma unroll
        for (int mi = 0; mi < 4; mi++)
            #pragma unroll
            for (int r = 0; r < 4; r++) cbl[mi * 4 + r] = cb[mi * 16 + kg * 4 + r];
        #pragma unroll
        for (int mi = 0; mi < 4; mi++) {
            #pragma unroll
            for (int ti = 0; ti < 4; ti++) {
                const int t = t0w + ti * 16 + lr;
                short4v yv;
                #pragma unroll
                for (int r = 0; r < 4; r++)
                    yv[r] = bf16bits(fmaxf(acc[mi][ti][r] + cbl[mi * 4 + r], 0.f));
                const int addr = t * 128 + ((mi * 32 + kg * 8) ^ ((t & 7) << 4));
                *(short4v*)((char*)xs + addr) = yv;
            }
        }
    }
    __syncthreads();

    f32x4 acc2[4][4];
    #pragma unroll
    for (int mi = 0; mi < 4; mi++)
        #pragma unroll
        for (int ti = 0; ti < 4; ti++)
            acc2[mi][ti] = (f32x4){0.f, 0.f, 0.f, 0.f};

    const short* gAp = (const short*)gA;
    #pragma unroll
    for (int ks = 0; ks < 2; ks++) {
        short8 af[4], bfr[4];
        #pragma unroll
        for (int mi = 0; mi < 4; mi++)
            af[mi] = *(const short8*)(gAp + ((mi * 16 + lr) * 64 + ks * 32 + kg * 8));
        #pragma unroll
        for (int ti = 0; ti < 4; ti++) {
            const int t = t0w + ti * 16 + lr;
            const int addr = t * 128 + ((ks * 64 + kg * 16) ^ ((t & 7) << 4));
            bfr[ti] = *(const short8*)((const char*)xs + addr);
        }
        #pragma unroll
        for (int ti = 0; ti < 4; ti++)
            #pragma unroll
            for (int mi = 0; mi < 4; mi++)
                acc2[mi][ti] = __builtin_amdgcn_mfma_f32_16x16x32_bf16(af[mi], bfr[ti], acc2[mi][ti], 0, 0, 0);
    }

    #pragma unroll
    for (int mi = 0; mi < 4; mi++) {
        #pragma unroll
        for (int r = 0; r < 4; r++) {
            const int h = mi * 16 + kg * 4 + r;
            bf16* orow = s_out + ((size_t)(lb * 64 + h) * NN + n) * TT + t0w + lr;
            #pragma unroll
            for (int ti = 0; ti < 4; ti++)
                orow[ti * 16] = __float2bfloat16(acc2[mi][ti][r]);
        }
    }
}

// ---------------- kernel 5: mean (from partials) + MLP ----------------
__global__ __launch_bounds__(64) void k_mlp(
    const float* __restrict__ pf, int nbh,
    const float* __restrict__ w1, const float* __restrict__ b1,
    const float* __restrict__ w2, const float* __restrict__ b2,
    float* __restrict__ out)
{
    __shared__ float mm[64];
    __shared__ float hid[32];
    const int n = blockIdx.x, lb = blockIdx.y, tid = threadIdx.x;

    const size_t stride = (size_t)nbh * NN;
    const size_t idx = (size_t)(lb * 64 + tid) * NN + n;
    float s = pf[idx] + pf[stride + idx] + pf[2 * stride + idx] + pf[3 * stride + idx];
    mm[tid] = s * (1.f / 256.f);
    __syncthreads();
    if (tid < 32) {
        float a = b1[tid];
        #pragma unroll
        for (int c = 0; c < 64; c++) a += mm[c] * w1[c * 32 + tid];
        hid[tid] = fmaxf(a, 0.f);
    }
    __syncthreads();
    if (tid == 0) {
        float a = b2[0];
        #pragma unroll
        for (int j = 0; j < 32; j++) a += hid[j] * w2[j];
        out[lb * NN + n] = a;
    }
}

extern "C" void kernel_launch(void* const* d_in, const int* in_sizes, int n_in,
                              void* d_out, int out_size, void* d_ws, size_t ws_size,
                              hipStream_t stream) {
    const float* x       = (const float*)d_in[0];
    const float* adj     = (const float*)d_in[1];
    const float* conv_w1 = (const float*)d_in[2];
    const float* conv_b1 = (const float*)d_in[3];
    const float* conv_w2 = (const float*)d_in[4];
    const float* conv_b2 = (const float*)d_in[5];
    const float* gcn_w1  = (const float*)d_in[6];
    const float* gcn_b1  = (const float*)d_in[7];
    const float* gcn_w2  = (const float*)d_in[8];
    const float* gcn_b2  = (const float*)d_in[9];
    const float* bn_g1   = (const float*)d_in[10];
    const float* bn_be1  = (const float*)d_in[11];
    const float* bn_m1   = (const float*)d_in[12];
    const float* bn_v1   = (const float*)d_in[13];
    const float* bn_g2   = (const float*)d_in[14];
    const float* bn_be2  = (const float*)d_in[15];
    const float* bn_m2   = (const float*)d_in[16];
    const float* bn_v2   = (const float*)d_in[17];
    const float* out_w1  = (const float*)d_in[18];
    const float* out_b1  = (const float*)d_in[19];
    const float* out_w2  = (const float*)d_in[20];
    const float* out_b2  = (const float*)d_in[21];
    float* out = (float*)d_out;

    const size_t per_b = (size_t)HH * NN * TT;             // 8,192,000 elems/batch
    const size_t reserve = 1 << 20;
    const size_t bytes_per_b_both = per_b * 2 * 2;
    int chunk = (int)((ws_size > reserve ? ws_size - reserve : 0) / bytes_per_b_both);
    if (chunk > BB) chunk = BB;
    if (chunk < 1) chunk = 1;

    char* ws = (char*)d_ws;
    bf16* adjb = (bf16*)ws;                                // 524,288 B
    bf16* wA2  = (bf16*)(ws + 0x80000);                    // 24,576 B
    bf16* gA2  = (bf16*)(ws + 0x80000 + 24576);            // 8,192 B
    bf16* wA1  = (bf16*)(ws + 0x80000 + 32768);            // 4,096 B
    bf16* gA1  = (bf16*)(ws + 0x80000 + 36864);            // 8,192 B
    bf16* bufA = (bf16*)(ws + reserve);
    bf16* bufB = bufA + (size_t)chunk * per_b;

    k_prep_adj<<<1024, 256, 0, stream>>>(adj, adjb);
    k_prep_weights<<<88, 256, 0, stream>>>(conv_w1, gcn_w1, conv_w2, gcn_w2,
                                           wA1, gA1, wA2, gA2);

    for (int b0 = 0; b0 < BB; b0 += chunk) {
        const int nb = (BB - b0) < chunk ? (BB - b0) : chunk;
        const int nbh = nb * 64;
        float* pf = (float*)bufB;   // bufB is dead during layer-2 adj + mlp

        k_conv_mfma1<<<dim3(NN, nb), 256, 0, stream>>>(
            x + (size_t)b0 * NN * TT * FIN, wA1, gA1, conv_b1, bufA);

        k_adj_mfma<false><<<dim3(8 * nbh), 256, 0, stream>>>(
            bufA, adjb, gcn_b1, bn_g1, bn_be1, bn_m1, bn_v1, bufB, nullptr, nbh);

        k_conv_mfma2<<<dim3(NN, nb), 256, 0, stream>>>(
            bufB, wA2, gA2, conv_b2, bufA);

        k_adj_mfma<true><<<dim3(8 * nbh), 256, 0, stream>>>(
            bufA, adjb, gcn_b2, bn_g2, bn_be2, bn_m2, bn_v2, nullptr, pf, nbh);

        k_mlp<<<dim3(NN, nb), 64, 0, stream>>>(
            pf, nbh, out_w1, out_b1, out_w2, out_b2, out + (size_t)b0 * NN);
    }
}

// Round 16
// 662.240 us; speedup vs baseline: 1.4001x; 1.1271x over previous
//
#include <hip/hip_runtime.h>
#include <hip/hip_bf16.h>

// SpatioTemporalGNN: B=16, N=500, T=256, F_IN=8, H=64, K=3, OUT=1
// rev 16 = rev 12 (708us anchor) + k_adj_mfma retiled 128x128 -> 256m x 128t
// (512 threads, 8 waves 4m x 2t, wave-tile 64x64 unchanged). Rationale: the
// B-transpose scatter cost scales with bytes staged; doubling the m-tile
// halves how often each S-tile is staged. Frag maps, SWZ_T, acc shape,
// epilogues unchanged. XCD decode: 2 m-tiles per (bh,t-half) share an XCD.
// rev-13/14/15 lessons: B-scatter rewrites, direct-global A, and reg
// prefetch (occupancy loss) all regress — amortization is the lever.

#define BB 16
#define NN 500
#define TT 256
#define FIN 8
#define HH 64

using bf16 = __hip_bfloat16;
typedef __attribute__((ext_vector_type(8))) short short8;
typedef __attribute__((ext_vector_type(4))) short short4v;
typedef __attribute__((ext_vector_type(4))) float f32x4;

static __device__ __forceinline__ short bf16bits(float v) {
    __hip_bfloat16 h = __float2bfloat16(v);
    return *reinterpret_cast<short*>(&h);
}

// ---------------- prep: adj -> padded bf16 [512][512] ----------------
__global__ __launch_bounds__(256) void k_prep_adj(
    const float* __restrict__ adj, bf16* __restrict__ adjb)
{
    int i = blockIdx.x * 256 + threadIdx.x;
    if (i < 512 * 512) {
        int r = i >> 9, c = i & 511;
        float v = (r < NN && c < NN) ? adj[r * NN + c] : 0.f;
        adjb[i] = __float2bfloat16(v);
    }
}

// ---------------- prep: pack all conv/gcn weights to bf16 MFMA-A layouts ----------------
__global__ __launch_bounds__(256) void k_prep_weights(
    const float* __restrict__ cw1, const float* __restrict__ gw1,
    const float* __restrict__ w2,  const float* __restrict__ gw2,
    bf16* __restrict__ wA1, bf16* __restrict__ gA1,
    bf16* __restrict__ wA2, bf16* __restrict__ gA2)
{
    int i = blockIdx.x * 256 + threadIdx.x;
    if (i < 2048) {
        int h = i >> 5, kp = i & 31, kk = kp >> 3, f = kp & 7;
        wA1[i] = __float2bfloat16(kk < 3 ? cw1[(h * 8 + f) * 3 + kk] : 0.f);
    } else if (i < 6144) {
        int j = i - 2048, h = j >> 6, c = j & 63;
        gA1[j] = __float2bfloat16(gw1[c * 64 + h]);
    } else if (i < 18432) {
        int j = i - 6144, kk = j / 4096, r = j & 4095, co = r >> 6, ci = r & 63;
        wA2[j] = __float2bfloat16(w2[(co * 64 + ci) * 3 + kk]);
    } else if (i < 22528) {
        int j = i - 18432, h = j >> 6, c = j & 63;
        gA2[j] = __float2bfloat16(gw2[c * 64 + h]);
    }
}

// ---------------- kernel 1: conv1 + relu + support1 via MFMA ----------------
__global__ __launch_bounds__(256) void k_conv_mfma1(
    const float* __restrict__ x, const bf16* __restrict__ wA1,
    const bf16* __restrict__ gA1, const float* __restrict__ cb,
    bf16* __restrict__ s_out)
{
    __shared__ __align__(16) short xs[256 * 64];   // 32 KB, pitch 128 B, swizzled

    const int tid = threadIdx.x;
    const int n = blockIdx.x, lb = blockIdx.y;
    const int lane = tid & 63, w = tid >> 6;
    const int lr = lane & 15, kg = lane >> 4;
    const int t0w = w * 64;

    {
        const float4* gx = (const float4*)(x + (size_t)(lb * NN + n) * (TT * FIN) + tid * 8);
        float4 a = gx[0], b = gx[1];
        short8 v;
        v[0] = bf16bits(a.x); v[1] = bf16bits(a.y); v[2] = bf16bits(a.z); v[3] = bf16bits(a.w);
        v[4] = bf16bits(b.x); v[5] = bf16bits(b.y); v[6] = bf16bits(b.z); v[7] = bf16bits(b.w);
        const int t = tid;
        *(short8*)((char*)xs + t * 128 + (16 ^ ((t & 7) << 4))) = v;
        if (t < 255)
            *(short8*)((char*)xs + (t + 1) * 128 + (0 ^ (((t + 1) & 7) << 4))) = v;
        if (t > 0)
            *(short8*)((char*)xs + (t - 1) * 128 + (32 ^ (((t - 1) & 7) << 4))) = v;
        short8 z = {0, 0, 0, 0, 0, 0, 0, 0};
        *(short8*)((char*)xs + t * 128 + (48 ^ ((t & 7) << 4))) = z;
        if (t == 0)   *(short8*)((char*)xs + 0 * 128 + (0 ^ 0)) = z;
        if (t == 255) *(short8*)((char*)xs + 255 * 128 + (32 ^ ((255 & 7) << 4))) = z;
    }
    __syncthreads();

    f32x4 acc[4][4];
    #pragma unroll
    for (int mi = 0; mi < 4; mi++)
        #pragma unroll
        for (int ti = 0; ti < 4; ti++)
            acc[mi][ti] = (f32x4){0.f, 0.f, 0.f, 0.f};

    const short* wAp = (const short*)wA1;
    {
        short8 af[4], bfr[4];
        #pragma unroll
        for (int mi = 0; mi < 4; mi++)
            af[mi] = *(const short8*)(wAp + (mi * 16 + lr) * 32 + kg * 8);
        #pragma unroll
        for (int ti = 0; ti < 4; ti++) {
            const int row = t0w + ti * 16 + lr;
            bfr[ti] = *(const short8*)((const char*)xs + row * 128 + ((kg * 16) ^ ((row & 7) << 4)));
        }
        #pragma unroll
        for (int ti = 0; ti < 4; ti++)
            #pragma unroll
            for (int mi = 0; mi < 4; mi++)
                acc[mi][ti] = __builtin_amdgcn_mfma_f32_16x16x32_bf16(af[mi], bfr[ti], acc[mi][ti], 0, 0, 0);
    }
    __syncthreads();

    {
        float cbl[16];
        #pragma unroll
        for (int mi = 0; mi < 4; mi++)
            #pragma unroll
            for (int r = 0; r < 4; r++) cbl[mi * 4 + r] = cb[mi * 16 + kg * 4 + r];
        #pragma unroll
        for (int mi = 0; mi < 4; mi++) {
            #pragma unroll
            for (int ti = 0; ti < 4; ti++) {
                const int t = t0w + ti * 16 + lr;
                short4v yv;
                #pragma unroll
                for (int r = 0; r < 4; r++)
                    yv[r] = bf16bits(fmaxf(acc[mi][ti][r] + cbl[mi * 4 + r], 0.f));
                *(short4v*)((char*)xs + t * 128 + ((mi * 32 + kg * 8) ^ ((t & 7) << 4))) = yv;
            }
        }
    }
    __syncthreads();

    f32x4 acc2[4][4];
    #pragma unroll
    for (int mi = 0; mi < 4; mi++)
        #pragma unroll
        for (int ti = 0; ti < 4; ti++)
            acc2[mi][ti] = (f32x4){0.f, 0.f, 0.f, 0.f};

    const short* gAp = (const short*)gA1;
    #pragma unroll
    for (int ks = 0; ks < 2; ks++) {
        short8 af[4], bfr[4];
        #pragma unroll
        for (int mi = 0; mi < 4; mi++)
            af[mi] = *(const short8*)(gAp + (mi * 16 + lr) * 64 + ks * 32 + kg * 8);
        #pragma unroll
        for (int ti = 0; ti < 4; ti++) {
            const int t = t0w + ti * 16 + lr;
            bfr[ti] = *(const short8*)((const char*)xs + t * 128 + ((ks * 64 + kg * 16) ^ ((t & 7) << 4)));
        }
        #pragma unroll
        for (int ti = 0; ti < 4; ti++)
            #pragma unroll
            for (int mi = 0; mi < 4; mi++)
                acc2[mi][ti] = __builtin_amdgcn_mfma_f32_16x16x32_bf16(af[mi], bfr[ti], acc2[mi][ti], 0, 0, 0);
    }

    #pragma unroll
    for (int mi = 0; mi < 4; mi++) {
        #pragma unroll
        for (int r = 0; r < 4; r++) {
            const int h = mi * 16 + kg * 4 + r;
            bf16* orow = s_out + ((size_t)(lb * 64 + h) * NN + n) * TT + t0w + lr;
            #pragma unroll
            for (int ti = 0; ti < 4; ti++)
                orow[ti * 16] = __float2bfloat16(acc2[mi][ti][r]);
        }
    }
}

// ---------------- kernel 2/4: adj GEMM via MFMA + bias + relu + BN ----------------
// 256m x 128t tile, 512 threads (8 waves, 4m x 2t). A staged [m 256][k 64]
// pitch 72 (b128). B^T staged [t 128][k 64] swizzled via scalar-u16 scatter.
// XCD-aware 1-D grid: id = xcd + 8*(mt + 2*gg); mt in {0,1} (m0 = mt*256).
#define SWZ_T(t) (((((t) & 7) ^ (((t) >> 5) << 1)) & 7) << 4)

template<bool MEAN>
__global__ __launch_bounds__(512) void k_adj_mfma(
    const bf16* __restrict__ s_in, const bf16* __restrict__ adjb,
    const float* __restrict__ gb, const float* __restrict__ bn_g,
    const float* __restrict__ bn_b, const float* __restrict__ bn_m,
    const float* __restrict__ bn_v, bf16* __restrict__ h_out,
    float* __restrict__ pf, int nbh)
{
    __shared__ __align__(16) short AsS[256 * 72];   // A [m 256][k 64], pitch 72 (36.9 KB)
    __shared__ __align__(16) short BtS[128 * 64];   // B^T [t 128][k 64], swizzled (16 KB)

    const int tid = threadIdx.x;
    const int id = blockIdx.x;
    const int xcd = id & 7;
    const int jj = id >> 3;
    const int mt = jj & 1;
    const int g = ((jj >> 1) << 3) + xcd;
    const int bh = g >> 1;
    const int m0 = mt * 256;
    const int t0 = (g & 1) * 128;
    const int h = bh & 63;

    const int lane = tid & 63;
    const int lr = lane & 15;
    const int kg = lane >> 4;
    const int w = tid >> 6;                 // 0..7
    const int wr = w >> 1, wc = w & 1;      // wr 0..3 (m 64-band), wc 0..1 (t half)

    f32x4 acc[4][4];
    #pragma unroll
    for (int mi = 0; mi < 4; mi++)
        #pragma unroll
        for (int ti = 0; ti < 4; ti++)
            acc[mi][ti] = (f32x4){0.f, 0.f, 0.f, 0.f};

    // staging maps (constant per thread), 512 threads:
    const int ar = tid >> 1, ah = (tid & 1) * 32;    // A: 256 rows, 32-k half, 64B/thread
    const int sk = tid >> 3, tseg = (tid & 7) * 16;  // B: 64 k-rows, 16-t segment, 32B/thread
    const bf16* sslice = s_in + (size_t)bh * (NN * TT) + t0;

    for (int rnd = 0; rnd < 8; rnd++) {
        const int k0 = rnd * 64;
        // ---- stage A: adjb[m0+ar][k0+ah .. +31] ----
        {
            const float4* src = (const float4*)(adjb + (size_t)(m0 + ar) * 512 + k0 + ah);
            float4* dst = (float4*)(AsS + ar * 72 + ah);
            dst[0] = src[0]; dst[1] = src[1]; dst[2] = src[2]; dst[3] = src[3];
        }
        // ---- stage B transposed: S[k0+sk][t0+tseg..+15] -> BtS[t][k] swizzled ----
        {
            const int kglob = k0 + sk;
            short8 v0, v1;
            if (kglob < NN) {
                const short8* gg = (const short8*)(sslice + (size_t)kglob * TT + tseg);
                v0 = gg[0]; v1 = gg[1];
            } else {
                v0 = (short8){0,0,0,0,0,0,0,0}; v1 = v0;
            }
            const int kslot = (sk >> 3) << 4;     // 16-B slot index of this k
            const int kfine = (sk & 7) * 2;       // byte within slot
            #pragma unroll
            for (int u = 0; u < 2; u++) {
                short8 v = (u == 0) ? v0 : v1;
                #pragma unroll
                for (int j = 0; j < 8; j++) {
                    const int t = tseg + u * 8 + j;
                    *(short*)((char*)BtS + t * 128 + (kslot ^ SWZ_T(t)) + kfine) = v[j];
                }
            }
        }
        __syncthreads();

        #pragma unroll
        for (int ks = 0; ks < 2; ks++) {
            short8 af[4], bfr[4];
            #pragma unroll
            for (int mi = 0; mi < 4; mi++)
                af[mi] = *(const short8*)(AsS + (wr * 64 + mi * 16 + lr) * 72 + ks * 32 + kg * 8);
            #pragma unroll
            for (int ti = 0; ti < 4; ti++) {
                const int t = wc * 64 + ti * 16 + lr;
                bfr[ti] = *(const short8*)((const char*)BtS + t * 128 + ((((ks * 4 + kg) << 4)) ^ SWZ_T(t)));
            }
            #pragma unroll
            for (int ti = 0; ti < 4; ti++)
                #pragma unroll
                for (int mi = 0; mi < 4; mi++)
                    acc[mi][ti] = __builtin_amdgcn_mfma_f32_16x16x32_bf16(af[mi], bfr[ti], acc[mi][ti], 0, 0, 0);
        }
        __syncthreads();
    }

    const float bias  = gb[h];
    const float scale = bn_g[h] / sqrtf(bn_v[h] + 1e-5f);
    const float shift = bn_b[h] - bn_m[h] * scale;

    if constexpr (!MEAN) {
        #pragma unroll
        for (int mi = 0; mi < 4; mi++) {
            const int mbase = m0 + wr * 64 + mi * 16 + kg * 4;
            #pragma unroll
            for (int r = 0; r < 4; r++) {
                const int m = mbase + r;
                if (m < NN) {
                    bf16* orow = h_out + ((size_t)bh * NN + m) * TT + t0 + wc * 64 + lr;
                    #pragma unroll
                    for (int ti = 0; ti < 4; ti++) {
                        float v = fmaxf(acc[mi][ti][r] + bias, 0.f);
                        orow[ti * 16] = __float2bfloat16(v * scale + shift);
                    }
                }
            }
        }
    } else {
        float sums[4][4];
        #pragma unroll
        for (int mi = 0; mi < 4; mi++)
            #pragma unroll
            for (int r = 0; r < 4; r++) {
                float s = 0.f;
                #pragma unroll
                for (int ti = 0; ti < 4; ti++)
                    s += fmaxf(acc[mi][ti][r] + bias, 0.f) * scale + shift;
                sums[mi][r] = s;
            }
        #pragma unroll
        for (int off = 1; off < 16; off <<= 1)
            #pragma unroll
            for (int mi = 0; mi < 4; mi++)
                #pragma unroll
                for (int r = 0; r < 4; r++)
                    sums[mi][r] += __shfl_xor(sums[mi][r], off, 64);
        if (lr == 0) {
            const size_t stride = (size_t)nbh * NN;
            float* pfb = pf + ((size_t)((g & 1) * 2 + wc)) * stride + (size_t)bh * NN;
            #pragma unroll
            for (int mi = 0; mi < 4; mi++) {
                const int m = m0 + wr * 64 + mi * 16 + kg * 4;
                if (m < NN) {
                    float4 v = make_float4(sums[mi][0], sums[mi][1], sums[mi][2], sums[mi][3]);
                    *(float4*)(pfb + m) = v;
                }
            }
        }
    }
}

// ---------------- kernel 3: conv2 + relu + support2 via MFMA (rev-12) ----------------
__global__ __launch_bounds__(256) void k_conv_mfma2(
    const bf16* __restrict__ hin, const bf16* __restrict__ wA,
    const bf16* __restrict__ gA, const float* __restrict__ cb,
    bf16* __restrict__ s_out)
{
    __shared__ __align__(16) short xs[258 * 64];   // 33 KB, swizzled

    const int tid = threadIdx.x;
    const int n = blockIdx.x, lb = blockIdx.y;
    const int lane = tid & 63, w = tid >> 6;
    const int lr = lane & 15, kg = lane >> 4;
    const int t0w = w * 64;

    const bf16* base = hin + ((size_t)lb * 64 * NN + n) * TT;

    {
        const int cin = tid >> 2, tq = (tid & 3) * 64;
        const short* gsrc = (const short*)(base + (size_t)cin * (NN * TT) + tq);
        #pragma unroll
        for (int i = 0; i < 8; i++) {
            short8 v = *(const short8*)(gsrc + i * 8);
            #pragma unroll
            for (int j = 0; j < 8; j++) {
                const int row = tq + i * 8 + j + 1;
                const int addr = row * 128 + ((cin * 2) ^ ((row & 7) << 4));
                *(short*)((char*)xs + addr) = v[j];
            }
        }
        if (tid < 64) {
            *(short*)((char*)xs + (tid * 2)) = 0;
            *(short*)((char*)xs + 257 * 128 + ((tid * 2) ^ 16)) = 0;
        }
    }
    __syncthreads();

    f32x4 acc[4][4];
    #pragma unroll
    for (int mi = 0; mi < 4; mi++)
        #pragma unroll
        for (int ti = 0; ti < 4; ti++)
            acc[mi][ti] = (f32x4){0.f, 0.f, 0.f, 0.f};

    const short* wAp = (const short*)wA;
    #pragma unroll
    for (int kk = 0; kk < 3; kk++) {
        #pragma unroll
        for (int ks = 0; ks < 2; ks++) {
            short8 af[4], bfr[4];
            #pragma unroll
            for (int mi = 0; mi < 4; mi++)
                af[mi] = *(const short8*)(wAp + ((kk * 64 + mi * 16 + lr) * 64 + ks * 32 + kg * 8));
            #pragma unroll
            for (int ti = 0; ti < 4; ti++) {
                const int row = t0w + ti * 16 + lr + kk;
                const int addr = row * 128 + ((ks * 64 + kg * 16) ^ ((row & 7) << 4));
                bfr[ti] = *(const short8*)((const char*)xs + addr);
            }
            #pragma unroll
            for (int ti = 0; ti < 4; ti++)
                #pragma unroll
                for (int mi = 0; mi < 4; mi++)
                    acc[mi][ti] = __builtin_amdgcn_mfma_f32_16x16x32_bf16(af[mi], bfr[ti], acc[mi][ti], 0, 0, 0);
        }
    }
    __syncthreads();

    {
        float cbl[16];
        #pragma unroll
        for (int mi = 0; mi < 4; mi++)
            #pragma unroll
            for (int r = 0; r < 4; r++) cbl[mi * 4 + r] = cb[mi * 16 + kg * 4 + r];
        #pragma unroll
        for (int mi = 0; mi < 4; mi++) {
            #pragma unroll
            for (int ti = 0; ti < 4; ti++) {
                const int t = t0w + ti * 16 + lr;
                short4v yv;
                #pragma unroll
                for (int r = 0; r < 4; r++)
                    yv[r] = bf16bits(fmaxf(acc[mi][ti][r] + cbl[mi * 4 + r], 0.f));
                const int addr = t * 128 + ((mi * 32 + kg * 8) ^ ((t & 7) << 4));
                *(short4v*)((char*)xs + addr) = yv;
            }
        }
    }
    __syncthreads();

    f32x4 acc2[4][4];
    #pragma unroll
    for (int mi = 0; mi < 4; mi++)
        #pragma unroll
        for (int ti = 0; ti < 4; ti++)
            acc2[mi][ti] = (f32x4){0.f, 0.f, 0.f, 0.f};

    const short* gAp = (const short*)gA;
    #pragma unroll
    for (int ks = 0; ks < 2; ks++) {
        short8 af[4], bfr[4];
        #pragma unroll
        for (int mi = 0; mi < 4; mi++)
            af[mi] = *(const short8*)(gAp + ((mi * 16 + lr) * 64 + ks * 32 + kg * 8));
        #pragma unroll
        for (int ti = 0; ti < 4; ti++) {
            const int t = t0w + ti * 16 + lr;
            const int addr = t * 128 + ((ks * 64 + kg * 16) ^ ((t & 7) << 4));
            bfr[ti] = *(const short8*)((const char*)xs + addr);
        }
        #pragma unroll
        for (int ti = 0; ti < 4; ti++)
            #pragma unroll
            for (int mi = 0; mi < 4; mi++)
                acc2[mi][ti] = __builtin_amdgcn_mfma_f32_16x16x32_bf16(af[mi], bfr[ti], acc2[mi][ti], 0, 0, 0);
    }

    #pragma unroll
    for (int mi = 0; mi < 4; mi++) {
        #pragma unroll
        for (int r = 0; r < 4; r++) {
            const int h = mi * 16 + kg * 4 + r;
            bf16* orow = s_out + ((size_t)(lb * 64 + h) * NN + n) * TT + t0w + lr;
            #pragma unroll
            for (int ti = 0; ti < 4; ti++)
                orow[ti * 16] = __float2bfloat16(acc2[mi][ti][r]);
        }
    }
}

// ---------------- kernel 5: mean (from partials) + MLP ----------------
__global__ __launch_bounds__(64) void k_mlp(
    const float* __restrict__ pf, int nbh,
    const float* __restrict__ w1, const float* __restrict__ b1,
    const float* __restrict__ w2, const float* __restrict__ b2,
    float* __restrict__ out)
{
    __shared__ float mm[64];
    __shared__ float hid[32];
    const int n = blockIdx.x, lb = blockIdx.y, tid = threadIdx.x;

    const size_t stride = (size_t)nbh * NN;
    const size_t idx = (size_t)(lb * 64 + tid) * NN + n;
    float s = pf[idx] + pf[stride + idx] + pf[2 * stride + idx] + pf[3 * stride + idx];
    mm[tid] = s * (1.f / 256.f);
    __syncthreads();
    if (tid < 32) {
        float a = b1[tid];
        #pragma unroll
        for (int c = 0; c < 64; c++) a += mm[c] * w1[c * 32 + tid];
        hid[tid] = fmaxf(a, 0.f);
    }
    __syncthreads();
    if (tid == 0) {
        float a = b2[0];
        #pragma unroll
        for (int j = 0; j < 32; j++) a += hid[j] * w2[j];
        out[lb * NN + n] = a;
    }
}

extern "C" void kernel_launch(void* const* d_in, const int* in_sizes, int n_in,
                              void* d_out, int out_size, void* d_ws, size_t ws_size,
                              hipStream_t stream) {
    const float* x       = (const float*)d_in[0];
    const float* adj     = (const float*)d_in[1];
    const float* conv_w1 = (const float*)d_in[2];
    const float* conv_b1 = (const float*)d_in[3];
    const float* conv_w2 = (const float*)d_in[4];
    const float* conv_b2 = (const float*)d_in[5];
    const float* gcn_w1  = (const float*)d_in[6];
    const float* gcn_b1  = (const float*)d_in[7];
    const float* gcn_w2  = (const float*)d_in[8];
    const float* gcn_b2  = (const float*)d_in[9];
    const float* bn_g1   = (const float*)d_in[10];
    const float* bn_be1  = (const float*)d_in[11];
    const float* bn_m1   = (const float*)d_in[12];
    const float* bn_v1   = (const float*)d_in[13];
    const float* bn_g2   = (const float*)d_in[14];
    const float* bn_be2  = (const float*)d_in[15];
    const float* bn_m2   = (const float*)d_in[16];
    const float* bn_v2   = (const float*)d_in[17];
    const float* out_w1  = (const float*)d_in[18];
    const float* out_b1  = (const float*)d_in[19];
    const float* out_w2  = (const float*)d_in[20];
    const float* out_b2  = (const float*)d_in[21];
    float* out = (float*)d_out;

    const size_t per_b = (size_t)HH * NN * TT;             // 8,192,000 elems/batch
    const size_t reserve = 1 << 20;
    const size_t bytes_per_b_both = per_b * 2 * 2;
    int chunk = (int)((ws_size > reserve ? ws_size - reserve : 0) / bytes_per_b_both);
    if (chunk > BB) chunk = BB;
    if (chunk < 1) chunk = 1;

    char* ws = (char*)d_ws;
    bf16* adjb = (bf16*)ws;                                // 524,288 B
    bf16* wA2  = (bf16*)(ws + 0x80000);                    // 24,576 B
    bf16* gA2  = (bf16*)(ws + 0x80000 + 24576);            // 8,192 B
    bf16* wA1  = (bf16*)(ws + 0x80000 + 32768);            // 4,096 B
    bf16* gA1  = (bf16*)(ws + 0x80000 + 36864);            // 8,192 B
    bf16* bufA = (bf16*)(ws + reserve);
    bf16* bufB = bufA + (size_t)chunk * per_b;

    k_prep_adj<<<1024, 256, 0, stream>>>(adj, adjb);
    k_prep_weights<<<88, 256, 0, stream>>>(conv_w1, gcn_w1, conv_w2, gcn_w2,
                                           wA1, gA1, wA2, gA2);

    for (int b0 = 0; b0 < BB; b0 += chunk) {
        const int nb = (BB - b0) < chunk ? (BB - b0) : chunk;
        const int nbh = nb * 64;
        float* pf = (float*)bufB;   // bufB is dead during layer-2 adj + mlp

        k_conv_mfma1<<<dim3(NN, nb), 256, 0, stream>>>(
            x + (size_t)b0 * NN * TT * FIN, wA1, gA1, conv_b1, bufA);

        k_adj_mfma<false><<<dim3(4 * nbh), 512, 0, stream>>>(
            bufA, adjb, gcn_b1, bn_g1, bn_be1, bn_m1, bn_v1, bufB, nullptr, nbh);

        k_conv_mfma2<<<dim3(NN, nb), 256, 0, stream>>>(
            bufB, wA2, gA2, conv_b2, bufA);

        k_adj_mfma<true><<<dim3(4 * nbh), 512, 0, stream>>>(
            bufA, adjb, gcn_b2, bn_g2, bn_be2, bn_m2, bn_v2, nullptr, pf, nbh);

        k_mlp<<<dim3(NN, nb), 64, 0, stream>>>(
            pf, nbh, out_w1, out_b1, out_w2, out_b2, out + (size_t)b0 * NN);
    }
}

// Round 17
// 658.150 us; speedup vs baseline: 1.4088x; 1.0062x over previous
//
#include <hip/hip_runtime.h>
#include <hip/hip_bf16.h>

// SpatioTemporalGNN: B=16, N=500, T=256, F_IN=8, H=64, K=3, OUT=1
// rev 17 = rev 16 (662us anchor) + ONE change: k_conv_mfma2 swizzle extended
// to SWZ_R(row) = ((row&7) ^ (((row>>6)&3)<<1)) << 4 at ALL five LDS access
// sites. Fixes the 8-way staging-write conflict (4 t-segments shared row&7
// and every row starts at bank 0 -> 64 lanes in one 8-bank window; 7.17M
// conflict counter). Compute-phase reads see constant (row>>6)&3 per wave ->
// unchanged behavior. adj 256-tile (rev 16), conv1, mlp untouched.

#define BB 16
#define NN 500
#define TT 256
#define FIN 8
#define HH 64

using bf16 = __hip_bfloat16;
typedef __attribute__((ext_vector_type(8))) short short8;
typedef __attribute__((ext_vector_type(4))) short short4v;
typedef __attribute__((ext_vector_type(4))) float f32x4;

static __device__ __forceinline__ short bf16bits(float v) {
    __hip_bfloat16 h = __float2bfloat16(v);
    return *reinterpret_cast<short*>(&h);
}

// ---------------- prep: adj -> padded bf16 [512][512] ----------------
__global__ __launch_bounds__(256) void k_prep_adj(
    const float* __restrict__ adj, bf16* __restrict__ adjb)
{
    int i = blockIdx.x * 256 + threadIdx.x;
    if (i < 512 * 512) {
        int r = i >> 9, c = i & 511;
        float v = (r < NN && c < NN) ? adj[r * NN + c] : 0.f;
        adjb[i] = __float2bfloat16(v);
    }
}

// ---------------- prep: pack all conv/gcn weights to bf16 MFMA-A layouts ----------------
__global__ __launch_bounds__(256) void k_prep_weights(
    const float* __restrict__ cw1, const float* __restrict__ gw1,
    const float* __restrict__ w2,  const float* __restrict__ gw2,
    bf16* __restrict__ wA1, bf16* __restrict__ gA1,
    bf16* __restrict__ wA2, bf16* __restrict__ gA2)
{
    int i = blockIdx.x * 256 + threadIdx.x;
    if (i < 2048) {
        int h = i >> 5, kp = i & 31, kk = kp >> 3, f = kp & 7;
        wA1[i] = __float2bfloat16(kk < 3 ? cw1[(h * 8 + f) * 3 + kk] : 0.f);
    } else if (i < 6144) {
        int j = i - 2048, h = j >> 6, c = j & 63;
        gA1[j] = __float2bfloat16(gw1[c * 64 + h]);
    } else if (i < 18432) {
        int j = i - 6144, kk = j / 4096, r = j & 4095, co = r >> 6, ci = r & 63;
        wA2[j] = __float2bfloat16(w2[(co * 64 + ci) * 3 + kk]);
    } else if (i < 22528) {
        int j = i - 18432, h = j >> 6, c = j & 63;
        gA2[j] = __float2bfloat16(gw2[c * 64 + h]);
    }
}

// ---------------- kernel 1: conv1 + relu + support1 via MFMA ----------------
__global__ __launch_bounds__(256) void k_conv_mfma1(
    const float* __restrict__ x, const bf16* __restrict__ wA1,
    const bf16* __restrict__ gA1, const float* __restrict__ cb,
    bf16* __restrict__ s_out)
{
    __shared__ __align__(16) short xs[256 * 64];   // 32 KB, pitch 128 B, swizzled

    const int tid = threadIdx.x;
    const int n = blockIdx.x, lb = blockIdx.y;
    const int lane = tid & 63, w = tid >> 6;
    const int lr = lane & 15, kg = lane >> 4;
    const int t0w = w * 64;

    {
        const float4* gx = (const float4*)(x + (size_t)(lb * NN + n) * (TT * FIN) + tid * 8);
        float4 a = gx[0], b = gx[1];
        short8 v;
        v[0] = bf16bits(a.x); v[1] = bf16bits(a.y); v[2] = bf16bits(a.z); v[3] = bf16bits(a.w);
        v[4] = bf16bits(b.x); v[5] = bf16bits(b.y); v[6] = bf16bits(b.z); v[7] = bf16bits(b.w);
        const int t = tid;
        *(short8*)((char*)xs + t * 128 + (16 ^ ((t & 7) << 4))) = v;
        if (t < 255)
            *(short8*)((char*)xs + (t + 1) * 128 + (0 ^ (((t + 1) & 7) << 4))) = v;
        if (t > 0)
            *(short8*)((char*)xs + (t - 1) * 128 + (32 ^ (((t - 1) & 7) << 4))) = v;
        short8 z = {0, 0, 0, 0, 0, 0, 0, 0};
        *(short8*)((char*)xs + t * 128 + (48 ^ ((t & 7) << 4))) = z;
        if (t == 0)   *(short8*)((char*)xs + 0 * 128 + (0 ^ 0)) = z;
        if (t == 255) *(short8*)((char*)xs + 255 * 128 + (32 ^ ((255 & 7) << 4))) = z;
    }
    __syncthreads();

    f32x4 acc[4][4];
    #pragma unroll
    for (int mi = 0; mi < 4; mi++)
        #pragma unroll
        for (int ti = 0; ti < 4; ti++)
            acc[mi][ti] = (f32x4){0.f, 0.f, 0.f, 0.f};

    const short* wAp = (const short*)wA1;
    {
        short8 af[4], bfr[4];
        #pragma unroll
        for (int mi = 0; mi < 4; mi++)
            af[mi] = *(const short8*)(wAp + (mi * 16 + lr) * 32 + kg * 8);
        #pragma unroll
        for (int ti = 0; ti < 4; ti++) {
            const int row = t0w + ti * 16 + lr;
            bfr[ti] = *(const short8*)((const char*)xs + row * 128 + ((kg * 16) ^ ((row & 7) << 4)));
        }
        #pragma unroll
        for (int ti = 0; ti < 4; ti++)
            #pragma unroll
            for (int mi = 0; mi < 4; mi++)
                acc[mi][ti] = __builtin_amdgcn_mfma_f32_16x16x32_bf16(af[mi], bfr[ti], acc[mi][ti], 0, 0, 0);
    }
    __syncthreads();

    {
        float cbl[16];
        #pragma unroll
        for (int mi = 0; mi < 4; mi++)
            #pragma unroll
            for (int r = 0; r < 4; r++) cbl[mi * 4 + r] = cb[mi * 16 + kg * 4 + r];
        #pragma unroll
        for (int mi = 0; mi < 4; mi++) {
            #pragma unroll
            for (int ti = 0; ti < 4; ti++) {
                const int t = t0w + ti * 16 + lr;
                short4v yv;
                #pragma unroll
                for (int r = 0; r < 4; r++)
                    yv[r] = bf16bits(fmaxf(acc[mi][ti][r] + cbl[mi * 4 + r], 0.f));
                *(short4v*)((char*)xs + t * 128 + ((mi * 32 + kg * 8) ^ ((t & 7) << 4))) = yv;
            }
        }
    }
    __syncthreads();

    f32x4 acc2[4][4];
    #pragma unroll
    for (int mi = 0; mi < 4; mi++)
        #pragma unroll
        for (int ti = 0; ti < 4; ti++)
            acc2[mi][ti] = (f32x4){0.f, 0.f, 0.f, 0.f};

    const short* gAp = (const short*)gA1;
    #pragma unroll
    for (int ks = 0; ks < 2; ks++) {
        short8 af[4], bfr[4];
        #pragma unroll
        for (int mi = 0; mi < 4; mi++)
            af[mi] = *(const short8*)(gAp + (mi * 16 + lr) * 64 + ks * 32 + kg * 8);
        #pragma unroll
        for (int ti = 0; ti < 4; ti++) {
            const int t = t0w + ti * 16 + lr;
            bfr[ti] = *(const short8*)((const char*)xs + t * 128 + ((ks * 64 + kg * 16) ^ ((t & 7) << 4)));
        }
        #pragma unroll
        for (int ti = 0; ti < 4; ti++)
            #pragma unroll
            for (int mi = 0; mi < 4; mi++)
                acc2[mi][ti] = __builtin_amdgcn_mfma_f32_16x16x32_bf16(af[mi], bfr[ti], acc2[mi][ti], 0, 0, 0);
    }

    #pragma unroll
    for (int mi = 0; mi < 4; mi++) {
        #pragma unroll
        for (int r = 0; r < 4; r++) {
            const int h = mi * 16 + kg * 4 + r;
            bf16* orow = s_out + ((size_t)(lb * 64 + h) * NN + n) * TT + t0w + lr;
            #pragma unroll
            for (int ti = 0; ti < 4; ti++)
                orow[ti * 16] = __float2bfloat16(acc2[mi][ti][r]);
        }
    }
}

// ---------------- kernel 2/4: adj GEMM via MFMA + bias + relu + BN ----------------
// 256m x 128t tile, 512 threads (8 waves, 4m x 2t). rev-16 body.
#define SWZ_T(t) (((((t) & 7) ^ (((t) >> 5) << 1)) & 7) << 4)

template<bool MEAN>
__global__ __launch_bounds__(512) void k_adj_mfma(
    const bf16* __restrict__ s_in, const bf16* __restrict__ adjb,
    const float* __restrict__ gb, const float* __restrict__ bn_g,
    const float* __restrict__ bn_b, const float* __restrict__ bn_m,
    const float* __restrict__ bn_v, bf16* __restrict__ h_out,
    float* __restrict__ pf, int nbh)
{
    __shared__ __align__(16) short AsS[256 * 72];   // A [m 256][k 64], pitch 72 (36.9 KB)
    __shared__ __align__(16) short BtS[128 * 64];   // B^T [t 128][k 64], swizzled (16 KB)

    const int tid = threadIdx.x;
    const int id = blockIdx.x;
    const int xcd = id & 7;
    const int jj = id >> 3;
    const int mt = jj & 1;
    const int g = ((jj >> 1) << 3) + xcd;
    const int bh = g >> 1;
    const int m0 = mt * 256;
    const int t0 = (g & 1) * 128;
    const int h = bh & 63;

    const int lane = tid & 63;
    const int lr = lane & 15;
    const int kg = lane >> 4;
    const int w = tid >> 6;                 // 0..7
    const int wr = w >> 1, wc = w & 1;      // wr 0..3 (m 64-band), wc 0..1 (t half)

    f32x4 acc[4][4];
    #pragma unroll
    for (int mi = 0; mi < 4; mi++)
        #pragma unroll
        for (int ti = 0; ti < 4; ti++)
            acc[mi][ti] = (f32x4){0.f, 0.f, 0.f, 0.f};

    // staging maps (constant per thread), 512 threads:
    const int ar = tid >> 1, ah = (tid & 1) * 32;    // A: 256 rows, 32-k half, 64B/thread
    const int sk = tid >> 3, tseg = (tid & 7) * 16;  // B: 64 k-rows, 16-t segment, 32B/thread
    const bf16* sslice = s_in + (size_t)bh * (NN * TT) + t0;

    for (int rnd = 0; rnd < 8; rnd++) {
        const int k0 = rnd * 64;
        // ---- stage A: adjb[m0+ar][k0+ah .. +31] ----
        {
            const float4* src = (const float4*)(adjb + (size_t)(m0 + ar) * 512 + k0 + ah);
            float4* dst = (float4*)(AsS + ar * 72 + ah);
            dst[0] = src[0]; dst[1] = src[1]; dst[2] = src[2]; dst[3] = src[3];
        }
        // ---- stage B transposed: S[k0+sk][t0+tseg..+15] -> BtS[t][k] swizzled ----
        {
            const int kglob = k0 + sk;
            short8 v0, v1;
            if (kglob < NN) {
                const short8* gg = (const short8*)(sslice + (size_t)kglob * TT + tseg);
                v0 = gg[0]; v1 = gg[1];
            } else {
                v0 = (short8){0,0,0,0,0,0,0,0}; v1 = v0;
            }
            const int kslot = (sk >> 3) << 4;     // 16-B slot index of this k
            const int kfine = (sk & 7) * 2;       // byte within slot
            #pragma unroll
            for (int u = 0; u < 2; u++) {
                short8 v = (u == 0) ? v0 : v1;
                #pragma unroll
                for (int j = 0; j < 8; j++) {
                    const int t = tseg + u * 8 + j;
                    *(short*)((char*)BtS + t * 128 + (kslot ^ SWZ_T(t)) + kfine) = v[j];
                }
            }
        }
        __syncthreads();

        #pragma unroll
        for (int ks = 0; ks < 2; ks++) {
            short8 af[4], bfr[4];
            #pragma unroll
            for (int mi = 0; mi < 4; mi++)
                af[mi] = *(const short8*)(AsS + (wr * 64 + mi * 16 + lr) * 72 + ks * 32 + kg * 8);
            #pragma unroll
            for (int ti = 0; ti < 4; ti++) {
                const int t = wc * 64 + ti * 16 + lr;
                bfr[ti] = *(const short8*)((const char*)BtS + t * 128 + ((((ks * 4 + kg) << 4)) ^ SWZ_T(t)));
            }
            #pragma unroll
            for (int ti = 0; ti < 4; ti++)
                #pragma unroll
                for (int mi = 0; mi < 4; mi++)
                    acc[mi][ti] = __builtin_amdgcn_mfma_f32_16x16x32_bf16(af[mi], bfr[ti], acc[mi][ti], 0, 0, 0);
        }
        __syncthreads();
    }

    const float bias  = gb[h];
    const float scale = bn_g[h] / sqrtf(bn_v[h] + 1e-5f);
    const float shift = bn_b[h] - bn_m[h] * scale;

    if constexpr (!MEAN) {
        #pragma unroll
        for (int mi = 0; mi < 4; mi++) {
            const int mbase = m0 + wr * 64 + mi * 16 + kg * 4;
            #pragma unroll
            for (int r = 0; r < 4; r++) {
                const int m = mbase + r;
                if (m < NN) {
                    bf16* orow = h_out + ((size_t)bh * NN + m) * TT + t0 + wc * 64 + lr;
                    #pragma unroll
                    for (int ti = 0; ti < 4; ti++) {
                        float v = fmaxf(acc[mi][ti][r] + bias, 0.f);
                        orow[ti * 16] = __float2bfloat16(v * scale + shift);
                    }
                }
            }
        }
    } else {
        float sums[4][4];
        #pragma unroll
        for (int mi = 0; mi < 4; mi++)
            #pragma unroll
            for (int r = 0; r < 4; r++) {
                float s = 0.f;
                #pragma unroll
                for (int ti = 0; ti < 4; ti++)
                    s += fmaxf(acc[mi][ti][r] + bias, 0.f) * scale + shift;
                sums[mi][r] = s;
            }
        #pragma unroll
        for (int off = 1; off < 16; off <<= 1)
            #pragma unroll
            for (int mi = 0; mi < 4; mi++)
                #pragma unroll
                for (int r = 0; r < 4; r++)
                    sums[mi][r] += __shfl_xor(sums[mi][r], off, 64);
        if (lr == 0) {
            const size_t stride = (size_t)nbh * NN;
            float* pfb = pf + ((size_t)((g & 1) * 2 + wc)) * stride + (size_t)bh * NN;
            #pragma unroll
            for (int mi = 0; mi < 4; mi++) {
                const int m = m0 + wr * 64 + mi * 16 + kg * 4;
                if (m < NN) {
                    float4 v = make_float4(sums[mi][0], sums[mi][1], sums[mi][2], sums[mi][3]);
                    *(float4*)(pfb + m) = v;
                }
            }
        }
    }
}

// ---------------- kernel 3: conv2 + relu + support2 via MFMA ----------------
// Swizzle extended with t-segment bits: SWZ_R(row) folds (row>>6)&3 into the
// slot index so the 4 t-segments of the staging scatter hit disjoint banks.
// Applied identically at all 5 LDS access sites (rule #21).
#define SWZ_R(row) (((((row) & 7) ^ ((((row) >> 6) & 3) << 1)) & 7) << 4)

__global__ __launch_bounds__(256) void k_conv_mfma2(
    const bf16* __restrict__ hin, const bf16* __restrict__ wA,
    const bf16* __restrict__ gA, const float* __restrict__ cb,
    bf16* __restrict__ s_out)
{
    __shared__ __align__(16) short xs[258 * 64];   // 33 KB, swizzled

    const int tid = threadIdx.x;
    const int n = blockIdx.x, lb = blockIdx.y;
    const int lane = tid & 63, w = tid >> 6;
    const int lr = lane & 15, kg = lane >> 4;
    const int t0w = w * 64;

    const bf16* base = hin + ((size_t)lb * 64 * NN + n) * TT;

    {
        const int cin = tid >> 2, tq = (tid & 3) * 64;
        const short* gsrc = (const short*)(base + (size_t)cin * (NN * TT) + tq);
        #pragma unroll
        for (int i = 0; i < 8; i++) {
            short8 v = *(const short8*)(gsrc + i * 8);
            #pragma unroll
            for (int j = 0; j < 8; j++) {
                const int row = tq + i * 8 + j + 1;
                const int addr = row * 128 + ((cin * 2) ^ SWZ_R(row));
                *(short*)((char*)xs + addr) = v[j];
            }
        }
        if (tid < 64) {
            *(short*)((char*)xs + ((tid * 2) ^ SWZ_R(0))) = 0;
            *(short*)((char*)xs + 257 * 128 + ((tid * 2) ^ SWZ_R(257))) = 0;
        }
    }
    __syncthreads();

    f32x4 acc[4][4];
    #pragma unroll
    for (int mi = 0; mi < 4; mi++)
        #pragma unroll
        for (int ti = 0; ti < 4; ti++)
            acc[mi][ti] = (f32x4){0.f, 0.f, 0.f, 0.f};

    const short* wAp = (const short*)wA;
    #pragma unroll
    for (int kk = 0; kk < 3; kk++) {
        #pragma unroll
        for (int ks = 0; ks < 2; ks++) {
            short8 af[4], bfr[4];
            #pragma unroll
            for (int mi = 0; mi < 4; mi++)
                af[mi] = *(const short8*)(wAp + ((kk * 64 + mi * 16 + lr) * 64 + ks * 32 + kg * 8));
            #pragma unroll
            for (int ti = 0; ti < 4; ti++) {
                const int row = t0w + ti * 16 + lr + kk;
                const int addr = row * 128 + ((ks * 64 + kg * 16) ^ SWZ_R(row));
                bfr[ti] = *(const short8*)((const char*)xs + addr);
            }
            #pragma unroll
            for (int ti = 0; ti < 4; ti++)
                #pragma unroll
                for (int mi = 0; mi < 4; mi++)
                    acc[mi][ti] = __builtin_amdgcn_mfma_f32_16x16x32_bf16(af[mi], bfr[ti], acc[mi][ti], 0, 0, 0);
        }
    }
    __syncthreads();

    {
        float cbl[16];
        #pragma unroll
        for (int mi = 0; mi < 4; mi++)
            #pragma unroll
            for (int r = 0; r < 4; r++) cbl[mi * 4 + r] = cb[mi * 16 + kg * 4 + r];
        #pragma unroll
        for (int mi = 0; mi < 4; mi++) {
            #pragma unroll
            for (int ti = 0; ti < 4; ti++) {
                const int t = t0w + ti * 16 + lr;
                short4v yv;
                #pragma unroll
                for (int r = 0; r < 4; r++)
                    yv[r] = bf16bits(fmaxf(acc[mi][ti][r] + cbl[mi * 4 + r], 0.f));
                const int addr = t * 128 + ((mi * 32 + kg * 8) ^ SWZ_R(t));
                *(short4v*)((char*)xs + addr) = yv;
            }
        }
    }
    __syncthreads();

    f32x4 acc2[4][4];
    #pragma unroll
    for (int mi = 0; mi < 4; mi++)
        #pragma unroll
        for (int ti = 0; ti < 4; ti++)
            acc2[mi][ti] = (f32x4){0.f, 0.f, 0.f, 0.f};

    const short* gAp = (const short*)gA;
    #pragma unroll
    for (int ks = 0; ks < 2; ks++) {
        short8 af[4], bfr[4];
        #pragma unroll
        for (int mi = 0; mi < 4; mi++)
            af[mi] = *(const short8*)(gAp + ((mi * 16 + lr) * 64 + ks * 32 + kg * 8));
        #pragma unroll
        for (int ti = 0; ti < 4; ti++) {
            const int t = t0w + ti * 16 + lr;
            const int addr = t * 128 + ((ks * 64 + kg * 16) ^ SWZ_R(t));
            bfr[ti] = *(const short8*)((const char*)xs + addr);
        }
        #pragma unroll
        for (int ti = 0; ti < 4; ti++)
            #pragma unroll
            for (int mi = 0; mi < 4; mi++)
                acc2[mi][ti] = __builtin_amdgcn_mfma_f32_16x16x32_bf16(af[mi], bfr[ti], acc2[mi][ti], 0, 0, 0);
    }

    #pragma unroll
    for (int mi = 0; mi < 4; mi++) {
        #pragma unroll
        for (int r = 0; r < 4; r++) {
            const int h = mi * 16 + kg * 4 + r;
            bf16* orow = s_out + ((size_t)(lb * 64 + h) * NN + n) * TT + t0w + lr;
            #pragma unroll
            for (int ti = 0; ti < 4; ti++)
                orow[ti * 16] = __float2bfloat16(acc2[mi][ti][r]);
        }
    }
}

// ---------------- kernel 5: mean (from partials) + MLP ----------------
__global__ __launch_bounds__(64) void k_mlp(
    const float* __restrict__ pf, int nbh,
    const float* __restrict__ w1, const float* __restrict__ b1,
    const float* __restrict__ w2, const float* __restrict__ b2,
    float* __restrict__ out)
{
    __shared__ float mm[64];
    __shared__ float hid[32];
    const int n = blockIdx.x, lb = blockIdx.y, tid = threadIdx.x;

    const size_t stride = (size_t)nbh * NN;
    const size_t idx = (size_t)(lb * 64 + tid) * NN + n;
    float s = pf[idx] + pf[stride + idx] + pf[2 * stride + idx] + pf[3 * stride + idx];
    mm[tid] = s * (1.f / 256.f);
    __syncthreads();
    if (tid < 32) {
        float a = b1[tid];
        #pragma unroll
        for (int c = 0; c < 64; c++) a += mm[c] * w1[c * 32 + tid];
        hid[tid] = fmaxf(a, 0.f);
    }
    __syncthreads();
    if (tid == 0) {
        float a = b2[0];
        #pragma unroll
        for (int j = 0; j < 32; j++) a += hid[j] * w2[j];
        out[lb * NN + n] = a;
    }
}

extern "C" void kernel_launch(void* const* d_in, const int* in_sizes, int n_in,
                              void* d_out, int out_size, void* d_ws, size_t ws_size,
                              hipStream_t stream) {
    const float* x       = (const float*)d_in[0];
    const float* adj     = (const float*)d_in[1];
    const float* conv_w1 = (const float*)d_in[2];
    const float* conv_b1 = (const float*)d_in[3];
    const float* conv_w2 = (const float*)d_in[4];
    const float* conv_b2 = (const float*)d_in[5];
    const float* gcn_w1  = (const float*)d_in[6];
    const float* gcn_b1  = (const float*)d_in[7];
    const float* gcn_w2  = (const float*)d_in[8];
    const float* gcn_b2  = (const float*)d_in[9];
    const float* bn_g1   = (const float*)d_in[10];
    const float* bn_be1  = (const float*)d_in[11];
    const float* bn_m1   = (const float*)d_in[12];
    const float* bn_v1   = (const float*)d_in[13];
    const float* bn_g2   = (const float*)d_in[14];
    const float* bn_be2  = (const float*)d_in[15];
    const float* bn_m2   = (const float*)d_in[16];
    const float* bn_v2   = (const float*)d_in[17];
    const float* out_w1  = (const float*)d_in[18];
    const float* out_b1  = (const float*)d_in[19];
    const float* out_w2  = (const float*)d_in[20];
    const float* out_b2  = (const float*)d_in[21];
    float* out = (float*)d_out;

    const size_t per_b = (size_t)HH * NN * TT;             // 8,192,000 elems/batch
    const size_t reserve = 1 << 20;
    const size_t bytes_per_b_both = per_b * 2 * 2;
    int chunk = (int)((ws_size > reserve ? ws_size - reserve : 0) / bytes_per_b_both);
    if (chunk > BB) chunk = BB;
    if (chunk < 1) chunk = 1;

    char* ws = (char*)d_ws;
    bf16* adjb = (bf16*)ws;                                // 524,288 B
    bf16* wA2  = (bf16*)(ws + 0x80000);                    // 24,576 B
    bf16* gA2  = (bf16*)(ws + 0x80000 + 24576);            // 8,192 B
    bf16* wA1  = (bf16*)(ws + 0x80000 + 32768);            // 4,096 B
    bf16* gA1  = (bf16*)(ws + 0x80000 + 36864);            // 8,192 B
    bf16* bufA = (bf16*)(ws + reserve);
    bf16* bufB = bufA + (size_t)chunk * per_b;

    k_prep_adj<<<1024, 256, 0, stream>>>(adj, adjb);
    k_prep_weights<<<88, 256, 0, stream>>>(conv_w1, gcn_w1, conv_w2, gcn_w2,
                                           wA1, gA1, wA2, gA2);

    for (int b0 = 0; b0 < BB; b0 += chunk) {
        const int nb = (BB - b0) < chunk ? (BB - b0) : chunk;
        const int nbh = nb * 64;
        float* pf = (float*)bufB;   // bufB is dead during layer-2 adj + mlp

        k_conv_mfma1<<<dim3(NN, nb), 256, 0, stream>>>(
            x + (size_t)b0 * NN * TT * FIN, wA1, gA1, conv_b1, bufA);

        k_adj_mfma<false><<<dim3(4 * nbh), 512, 0, stream>>>(
            bufA, adjb, gcn_b1, bn_g1, bn_be1, bn_m1, bn_v1, bufB, nullptr, nbh);

        k_conv_mfma2<<<dim3(NN, nb), 256, 0, stream>>>(
            bufB, wA2, gA2, conv_b2, bufA);

        k_adj_mfma<true><<<dim3(4 * nbh), 512, 0, stream>>>(
            bufA, adjb, gcn_b2, bn_g2, bn_be2, bn_m2, bn_v2, nullptr, pf, nbh);

        k_mlp<<<dim3(NN, nb), 64, 0, stream>>>(
            pf, nbh, out_w1, out_b1, out_w2, out_b2, out + (size_t)b0 * NN);
    }
}